// Round 1
// baseline (1186.227 us; speedup 1.0000x reference)
//
#include <hip/hip_runtime.h>
#include <hip/hip_bf16.h>

#define B 8
#define N 25200
#define ROW 85
#define NC 80
#define K 2048
#define MAXDET 300
#define NBUCKET 16384
#define CAND_CAP 4096

// ---------------------------------------------------------------------------
// Kernel 1: zero histogram + candidate counters (ws is poisoned 0xAA each call)
// ---------------------------------------------------------------------------
__global__ void nms_zero_kernel(unsigned* __restrict__ hist, unsigned* __restrict__ cnt) {
    int t = blockIdx.x * blockDim.x + threadIdx.x;
    if (t < B * NBUCKET) hist[t] = 0u;
    if (t < B) cnt[t] = 0u;
}

// ---------------------------------------------------------------------------
// Kernel 2: per-box score/cls/validity + histogram of quantized scores
// ---------------------------------------------------------------------------
__global__ void nms_score_kernel(const float* __restrict__ x,
                                 float* __restrict__ scores,
                                 int* __restrict__ cls_id,
                                 unsigned* __restrict__ hist) {
    int t = blockIdx.x * blockDim.x + threadIdx.x;
    if (t >= B * N) return;
    int b = t / N;
    const float* p = x + (size_t)t * ROW;
    float obj = p[4];
    float score = -1.0f;
    int cid = 0;
    if (obj > 0.3f) {
        float best = -1e30f;
        int bi = 0;
        #pragma unroll 8
        for (int c = 0; c < NC; ++c) {
            float v = __fmul_rn(p[5 + c], obj);   // exact, no FMA possible
            if (v > best) { best = v; bi = c; }   // first-max = np.argmax
        }
        cid = bi;
        if (best > 0.3f) {
            score = best;
            int q = (int)(__fmul_rn(best, 16384.0f));
            if (q > NBUCKET - 1) q = NBUCKET - 1;
            atomicAdd(&hist[b * NBUCKET + q], 1u);
        }
    }
    scores[t] = score;
    cls_id[t] = cid;
}

// ---------------------------------------------------------------------------
// Kernel 3: find threshold bucket per batch (one wave per batch, block=512)
// ---------------------------------------------------------------------------
__global__ void nms_thresh_kernel(const unsigned* __restrict__ hist,
                                  int* __restrict__ thresh) {
    int b = threadIdx.x >> 6;
    int lane = threadIdx.x & 63;
    const unsigned* h = hist + b * NBUCKET;
    int cum = 0;
    int t_found = -1;
    for (int g = 0; g < NBUCKET / 64 && t_found < 0; ++g) {
        int bucket = NBUCKET - 1 - g * 64 - lane;   // lane order = descending bucket
        unsigned c = h[bucket];
        unsigned pref = c;                          // inclusive prefix over lanes
        #pragma unroll
        for (int o = 1; o < 64; o <<= 1) {
            unsigned u = __shfl_up(pref, o, 64);
            if (lane >= o) pref += u;
        }
        unsigned total = __shfl(pref, 63, 64);
        if (cum + (int)total >= K) {
            bool hit = (cum + (int)pref) >= K;
            unsigned long long m = __ballot(hit);
            int firstlane = __ffsll(m) - 1;
            t_found = NBUCKET - 1 - g * 64 - firstlane;
        }
        cum += (int)total;
    }
    if (t_found < 0) t_found = 0;   // fewer than K valid (won't occur with this data)
    if (lane == 0) thresh[b] = t_found;
}

// ---------------------------------------------------------------------------
// Kernel 4: compact candidates (score,idx) with q >= threshold bucket
// ---------------------------------------------------------------------------
__global__ void nms_compact_kernel(const float* __restrict__ scores,
                                   const int* __restrict__ thresh,
                                   unsigned* __restrict__ cnt,
                                   float* __restrict__ cand_s,
                                   int* __restrict__ cand_i) {
    int t = blockIdx.x * blockDim.x + threadIdx.x;
    if (t >= B * N) return;
    int b = t / N;
    int i = t - b * N;
    float s = scores[t];
    if (s > 0.0f) {
        int q = (int)(__fmul_rn(s, 16384.0f));
        if (q > NBUCKET - 1) q = NBUCKET - 1;
        if (q >= thresh[b]) {
            unsigned pos = atomicAdd(&cnt[b], 1u);
            if (pos < CAND_CAP) {
                cand_s[b * CAND_CAP + pos] = s;
                cand_i[b * CAND_CAP + pos] = i;
            }
        }
    }
}

// ---------------------------------------------------------------------------
// Kernel 5: bitonic sort 4096 candidates in LDS (desc score, asc idx),
//           gather top-2048 boxes / cls / shifted boxes / areas
// ---------------------------------------------------------------------------
__global__ void __launch_bounds__(1024)
nms_sort_gather_kernel(const float* __restrict__ cand_s,
                       const int* __restrict__ cand_i,
                       const unsigned* __restrict__ cnt,
                       const float* __restrict__ x,
                       const int* __restrict__ cls_id,
                       float* __restrict__ top_s,
                       float* __restrict__ boxes,
                       int* __restrict__ clsk,
                       float* __restrict__ shifted,
                       float* __restrict__ area) {
    __shared__ float ss[CAND_CAP];
    __shared__ int   si[CAND_CAP];
    int b = blockIdx.x;
    unsigned n = cnt[b];
    if (n > CAND_CAP) n = CAND_CAP;
    for (int i = threadIdx.x; i < CAND_CAP; i += 1024) {
        if (i < (int)n) { ss[i] = cand_s[b * CAND_CAP + i]; si[i] = cand_i[b * CAND_CAP + i]; }
        else            { ss[i] = -1e30f; si[i] = 0x7FFFFFFF; }
    }
    __syncthreads();
    for (int k = 2; k <= CAND_CAP; k <<= 1) {
        for (int j = k >> 1; j > 0; j >>= 1) {
            for (int i = threadIdx.x; i < CAND_CAP; i += 1024) {
                int p = i ^ j;
                if (p > i) {
                    float s1 = ss[i], s2 = ss[p];
                    int   i1 = si[i], i2 = si[p];
                    // "i precedes p" in final order: score desc, idx asc
                    bool inOrder = (s1 > s2) || (s1 == s2 && i1 <= i2);
                    bool dirBestFirst = ((i & k) == 0);
                    bool doSwap = dirBestFirst ? (!inOrder) : inOrder;
                    if (doSwap) { ss[i] = s2; si[i] = i2; ss[p] = s1; si[p] = i1; }
                }
            }
            __syncthreads();
        }
    }
    // gather top K
    for (int r = threadIdx.x; r < K; r += 1024) {
        float s = ss[r];
        int idx = si[r];
        float x1, y1, x2, y2;
        int c;
        if (idx == 0x7FFFFFFF) {
            s = -1.0f; x1 = y1 = x2 = y2 = 0.0f; c = 0;
        } else {
            const float* p = x + ((size_t)b * N + idx) * ROW;
            float cx = p[0], cy = p[1], w = p[2], h = p[3];
            float hx = __fmul_rn(w, 0.5f);
            float hy = __fmul_rn(h, 0.5f);
            x1 = __fsub_rn(cx, hx); y1 = __fsub_rn(cy, hy);
            x2 = __fadd_rn(cx, hx); y2 = __fadd_rn(cy, hy);
            c = cls_id[b * N + idx];
        }
        int o = b * K + r;
        top_s[o] = s;
        boxes[o * 4 + 0] = x1; boxes[o * 4 + 1] = y1;
        boxes[o * 4 + 2] = x2; boxes[o * 4 + 3] = y2;
        clsk[o] = c;
        float sh = __fmul_rn((float)c, 4096.0f);  // exact (int*4096 < 2^24)
        float sx1 = __fadd_rn(x1, sh), sy1 = __fadd_rn(y1, sh);
        float sx2 = __fadd_rn(x2, sh), sy2 = __fadd_rn(y2, sh);
        shifted[o * 4 + 0] = sx1; shifted[o * 4 + 1] = sy1;
        shifted[o * 4 + 2] = sx2; shifted[o * 4 + 3] = sy2;
        area[o] = __fmul_rn(__fsub_rn(sx2, sx1), __fsub_rn(sy2, sy1));
    }
}

// ---------------------------------------------------------------------------
// Kernel 6: torchvision-style IoU bitmask. grid (jb=32, ib=32, b=8), block 64.
// mask[b][i][jb] bit jl set iff j = jb*64+jl, j > i, iou(i,j) > 0.6
// ---------------------------------------------------------------------------
__global__ void nms_mask_kernel(const float* __restrict__ shifted,
                                const float* __restrict__ area,
                                unsigned long long* __restrict__ mask) {
    int jb = blockIdx.x, ib = blockIdx.y, b = blockIdx.z;
    int t = threadIdx.x;   // 0..63
    int i = ib * 64 + t;
    unsigned long long* mrow = mask + ((size_t)b * K + i) * 32 + jb;
    if (jb < ib) { *mrow = 0ULL; return; }

    __shared__ float jbox[64][4];
    __shared__ float jarea[64];
    int j0 = jb * 64;
    {
        const float* sb = shifted + ((size_t)b * K + j0 + t) * 4;
        jbox[t][0] = sb[0]; jbox[t][1] = sb[1]; jbox[t][2] = sb[2]; jbox[t][3] = sb[3];
        jarea[t] = area[b * K + j0 + t];
    }
    __syncthreads();

    const float* ab = shifted + ((size_t)b * K + i) * 4;
    float ax1 = ab[0], ay1 = ab[1], ax2 = ab[2], ay2 = ab[3];
    float aarea = area[b * K + i];

    unsigned long long bits = 0ULL;
    for (int jl = 0; jl < 64; ++jl) {
        int j = j0 + jl;
        if (j > i) {
            float lx = fmaxf(ax1, jbox[jl][0]);
            float ly = fmaxf(ay1, jbox[jl][1]);
            float rx = fminf(ax2, jbox[jl][2]);
            float ry = fminf(ay2, jbox[jl][3]);
            float w = fmaxf(__fsub_rn(rx, lx), 0.0f);
            float h = fmaxf(__fsub_rn(ry, ly), 0.0f);
            float inter = __fmul_rn(w, h);
            // ((area_i + area_j) - inter) + 1e-9  -- exact ref order
            float denom = __fadd_rn(__fsub_rn(__fadd_rn(aarea, jarea[jl]), inter), 1e-9f);
            float iou = __fdiv_rn(inter, denom);
            if (iou > 0.6f) bits |= (1ULL << jl);
        }
    }
    *mrow = bits;
}

// ---------------------------------------------------------------------------
// Kernel 7: serial greedy reduce. One wave per batch.
// ---------------------------------------------------------------------------
__global__ void nms_reduce_kernel(const unsigned long long* __restrict__ mask,
                                  const float* __restrict__ top_s,
                                  unsigned* __restrict__ keep) {
    int b = blockIdx.x;
    int lane = threadIdx.x;   // 0..63
    __shared__ unsigned long long removed[32];
    if (lane < 32) removed[lane] = 0ULL;
    __syncthreads();
    for (int i = 0; i < K; ++i) {
        unsigned long long w = removed[i >> 6];
        bool k = (((w >> (i & 63)) & 1ULL) == 0ULL) && (top_s[b * K + i] > 0.0f);
        if (k && lane < 32) {
            removed[lane] |= mask[((size_t)b * K + i) * 32 + lane];
        }
        if (lane == 0) keep[b * K + i] = k ? 1u : 0u;
        __syncthreads();
    }
}

// ---------------------------------------------------------------------------
// Kernel 8: final top-300 + output write. One wave per batch.
// Kept entries (already score-descending) first, then non-kept by ascending
// position (matches jax top_k tie-break over the tied -1.0 values).
// ---------------------------------------------------------------------------
__global__ void nms_out_kernel(const unsigned* __restrict__ keep,
                               const float* __restrict__ top_s,
                               const float* __restrict__ boxes,
                               const int* __restrict__ clsk,
                               float* __restrict__ out) {
    int b = blockIdx.x;
    int lane = threadIdx.x;   // 0..63
    int total = 0;
    for (int c = 0; c < K / 64; ++c) {
        bool k = keep[b * K + c * 64 + lane] != 0u;
        unsigned long long m = __ballot(k);
        total += __popcll(m);
    }
    float* dets  = out + (size_t)b * MAXDET * 6;
    float* flags = out + (size_t)B * MAXDET * 6 + (size_t)b * MAXDET;
    unsigned long long below = (lane == 0) ? 0ULL : (~0ULL >> (64 - lane));
    int kc = 0, nc = 0;
    for (int c = 0; c < K / 64; ++c) {
        int i = c * 64 + lane;
        bool k = keep[b * K + i] != 0u;
        unsigned long long m = __ballot(k);
        int pc = __popcll(m);
        int slot = k ? (kc + __popcll(m & below))
                     : (total + nc + __popcll((~m) & below));
        if (slot < MAXDET) {
            int o = b * K + i;
            dets[slot * 6 + 0] = boxes[o * 4 + 0];
            dets[slot * 6 + 1] = boxes[o * 4 + 1];
            dets[slot * 6 + 2] = boxes[o * 4 + 2];
            dets[slot * 6 + 3] = boxes[o * 4 + 3];
            dets[slot * 6 + 4] = top_s[o];
            dets[slot * 6 + 5] = (float)clsk[o];
            flags[slot] = k ? 1.0f : 0.0f;
        }
        kc += pc;
        nc += 64 - pc;
    }
}

// ---------------------------------------------------------------------------
extern "C" void kernel_launch(void* const* d_in, const int* in_sizes, int n_in,
                              void* d_out, int out_size, void* d_ws, size_t ws_size,
                              hipStream_t stream) {
    const float* x = (const float*)d_in[0];
    float* out = (float*)d_out;

    char* ws = (char*)d_ws;
    size_t off = 0;
    auto alloc = [&](size_t bytes) -> void* {
        void* p = ws + off;
        off += bytes;
        off = (off + 255) & ~(size_t)255;
        return p;
    };

    float*    scores = (float*)    alloc((size_t)B * N * 4);
    int*      cls_id = (int*)      alloc((size_t)B * N * 4);
    unsigned* hist   = (unsigned*) alloc((size_t)B * NBUCKET * 4);
    unsigned* cnt    = (unsigned*) alloc((size_t)B * 4);
    int*      thresh = (int*)      alloc((size_t)B * 4);
    float*    cand_s = (float*)    alloc((size_t)B * CAND_CAP * 4);
    int*      cand_i = (int*)      alloc((size_t)B * CAND_CAP * 4);
    float*    top_s  = (float*)    alloc((size_t)B * K * 4);
    float*    boxes  = (float*)    alloc((size_t)B * K * 4 * 4);
    int*      clsk   = (int*)      alloc((size_t)B * K * 4);
    float*    shifted= (float*)    alloc((size_t)B * K * 4 * 4);
    float*    area   = (float*)    alloc((size_t)B * K * 4);
    unsigned long long* mask = (unsigned long long*) alloc((size_t)B * K * 32 * 8);
    unsigned* keep   = (unsigned*) alloc((size_t)B * K * 4);
    (void)ws_size; // needs ~7.4 MB

    int nb = (B * N + 255) / 256;
    nms_zero_kernel<<<(B * NBUCKET + 255) / 256, 256, 0, stream>>>(hist, cnt);
    nms_score_kernel<<<nb, 256, 0, stream>>>(x, scores, cls_id, hist);
    nms_thresh_kernel<<<1, 512, 0, stream>>>(hist, thresh);
    nms_compact_kernel<<<nb, 256, 0, stream>>>(scores, thresh, cnt, cand_s, cand_i);
    nms_sort_gather_kernel<<<B, 1024, 0, stream>>>(cand_s, cand_i, cnt, x, cls_id,
                                                   top_s, boxes, clsk, shifted, area);
    nms_mask_kernel<<<dim3(32, 32, B), 64, 0, stream>>>(shifted, area, mask);
    nms_reduce_kernel<<<B, 64, 0, stream>>>(mask, top_s, keep);
    nms_out_kernel<<<B, 64, 0, stream>>>(keep, top_s, boxes, clsk, out);
}

// Round 2
// 487.417 us; speedup vs baseline: 2.4337x; 2.4337x over previous
//
#include <hip/hip_runtime.h>
#include <hip/hip_bf16.h>

#define B 8
#define N 25200
#define ROW 85
#define NC 80
#define K 2048
#define MAXDET 300
#define NBUCKET 16384
#define CAND_CAP 4096
#define NCHUNK 32   /* K/64 */

// ---------------------------------------------------------------------------
// Kernel 1: zero histogram + candidate counters (ws is poisoned 0xAA each call)
// ---------------------------------------------------------------------------
__global__ void nms_zero_kernel(unsigned* __restrict__ hist, unsigned* __restrict__ cnt) {
    int t = blockIdx.x * blockDim.x + threadIdx.x;
    if (t < B * NBUCKET) hist[t] = 0u;
    if (t < B) cnt[t] = 0u;
}

// ---------------------------------------------------------------------------
// Kernel 2: per-box score/cls/validity + histogram of quantized scores
// ---------------------------------------------------------------------------
__global__ void nms_score_kernel(const float* __restrict__ x,
                                 float* __restrict__ scores,
                                 int* __restrict__ cls_id,
                                 unsigned* __restrict__ hist) {
    int t = blockIdx.x * blockDim.x + threadIdx.x;
    if (t >= B * N) return;
    int b = t / N;
    const float* p = x + (size_t)t * ROW;
    float obj = p[4];
    float score = -1.0f;
    int cid = 0;
    if (obj > 0.3f) {
        float best = -1e30f;
        int bi = 0;
        #pragma unroll 8
        for (int c = 0; c < NC; ++c) {
            float v = __fmul_rn(p[5 + c], obj);   // exact, no FMA possible
            if (v > best) { best = v; bi = c; }   // first-max = np.argmax
        }
        cid = bi;
        if (best > 0.3f) {
            score = best;
            int q = (int)(__fmul_rn(best, 16384.0f));
            if (q > NBUCKET - 1) q = NBUCKET - 1;
            atomicAdd(&hist[b * NBUCKET + q], 1u);
        }
    }
    scores[t] = score;
    cls_id[t] = cid;
}

// ---------------------------------------------------------------------------
// Kernel 3: threshold bucket per batch. One block per batch; histogram staged
// in LDS; two-level descending scan (256 group sums -> refine in group).
// ---------------------------------------------------------------------------
__global__ void __launch_bounds__(256)
nms_thresh_kernel(const unsigned* __restrict__ hist, int* __restrict__ thresh) {
    int b = blockIdx.x;
    int t = threadIdx.x, ln = t & 63, wv = t >> 6;
    __shared__ unsigned lh[NBUCKET];     // 64 KB
    __shared__ unsigned gsum[256];
    const uint4* src = (const uint4*)(hist + b * NBUCKET);
    uint4* dst = (uint4*)lh;
    for (int k = t; k < NBUCKET / 4; k += 256) dst[k] = src[k];
    __syncthreads();
    // group sums (rotated LDS reads -> 2-way conflicts only)
    unsigned s = 0;
    for (int k = 0; k < 64; ++k) s += lh[t * 64 + ((k + t) & 63)];
    gsum[t] = s;
    __syncthreads();
    if (wv == 0) {
        int cum = 0, found_g = -1, base_for_g = 0;
        for (int r = 0; r < 4 && found_g < 0; ++r) {
            int g = 255 - (r * 64 + ln);            // descending group order
            unsigned v = gsum[g];
            unsigned pref = v;
            #pragma unroll
            for (int o = 1; o < 64; o <<= 1) { unsigned u = __shfl_up(pref, o, 64); if (ln >= o) pref += u; }
            unsigned total = __shfl(pref, 63, 64);
            if (cum + (int)total >= K) {
                bool hit = (cum + (int)pref) >= K;
                unsigned long long m = __ballot(hit);
                int fl = __ffsll(m) - 1;
                found_g = 255 - (r * 64 + fl);
                unsigned pf = __shfl(pref, fl, 64);
                unsigned vv = __shfl(v, fl, 64);
                base_for_g = cum + (int)pf - (int)vv;  // cumulative above found group
            }
            cum += (int)total;
        }
        int T = 0;
        if (found_g >= 0) {
            int q = found_g * 64 + 63 - ln;          // descending bucket order
            unsigned v = lh[q];
            unsigned pref = v;
            #pragma unroll
            for (int o = 1; o < 64; o <<= 1) { unsigned u = __shfl_up(pref, o, 64); if (ln >= o) pref += u; }
            bool hit = (base_for_g + (int)pref) >= K;
            unsigned long long m = __ballot(hit);
            int fl = __ffsll(m) - 1;
            T = (fl >= 0) ? (found_g * 64 + 63 - fl) : 0;
        }
        if (ln == 0) thresh[b] = T;
    }
}

// ---------------------------------------------------------------------------
// Kernel 4: compact candidates (score,idx) with q >= threshold bucket
// ---------------------------------------------------------------------------
__global__ void nms_compact_kernel(const float* __restrict__ scores,
                                   const int* __restrict__ thresh,
                                   unsigned* __restrict__ cnt,
                                   float* __restrict__ cand_s,
                                   int* __restrict__ cand_i) {
    int t = blockIdx.x * blockDim.x + threadIdx.x;
    if (t >= B * N) return;
    int b = t / N;
    int i = t - b * N;
    float s = scores[t];
    if (s > 0.0f) {
        int q = (int)(__fmul_rn(s, 16384.0f));
        if (q > NBUCKET - 1) q = NBUCKET - 1;
        if (q >= thresh[b]) {
            unsigned pos = atomicAdd(&cnt[b], 1u);
            if (pos < CAND_CAP) {
                cand_s[b * CAND_CAP + pos] = s;
                cand_i[b * CAND_CAP + pos] = i;
            }
        }
    }
}

// ---------------------------------------------------------------------------
// Kernel 5: bitonic sort 4096 candidates in LDS (desc score, asc idx),
//           gather top-2048 boxes / cls / shifted boxes / areas
// ---------------------------------------------------------------------------
__global__ void __launch_bounds__(1024)
nms_sort_gather_kernel(const float* __restrict__ cand_s,
                       const int* __restrict__ cand_i,
                       const unsigned* __restrict__ cnt,
                       const float* __restrict__ x,
                       const int* __restrict__ cls_id,
                       float* __restrict__ top_s,
                       float* __restrict__ boxes,
                       int* __restrict__ clsk,
                       float* __restrict__ shifted,
                       float* __restrict__ area) {
    __shared__ float ss[CAND_CAP];
    __shared__ int   si[CAND_CAP];
    int b = blockIdx.x;
    unsigned n = cnt[b];
    if (n > CAND_CAP) n = CAND_CAP;
    for (int i = threadIdx.x; i < CAND_CAP; i += 1024) {
        if (i < (int)n) { ss[i] = cand_s[b * CAND_CAP + i]; si[i] = cand_i[b * CAND_CAP + i]; }
        else            { ss[i] = -1e30f; si[i] = 0x7FFFFFFF; }
    }
    __syncthreads();
    for (int k = 2; k <= CAND_CAP; k <<= 1) {
        for (int j = k >> 1; j > 0; j >>= 1) {
            for (int i = threadIdx.x; i < CAND_CAP; i += 1024) {
                int p = i ^ j;
                if (p > i) {
                    float s1 = ss[i], s2 = ss[p];
                    int   i1 = si[i], i2 = si[p];
                    bool inOrder = (s1 > s2) || (s1 == s2 && i1 <= i2);
                    bool dirBestFirst = ((i & k) == 0);
                    bool doSwap = dirBestFirst ? (!inOrder) : inOrder;
                    if (doSwap) { ss[i] = s2; si[i] = i2; ss[p] = s1; si[p] = i1; }
                }
            }
            __syncthreads();
        }
    }
    for (int r = threadIdx.x; r < K; r += 1024) {
        float s = ss[r];
        int idx = si[r];
        float x1, y1, x2, y2;
        int c;
        if (idx == 0x7FFFFFFF) {
            s = -1.0f; x1 = y1 = x2 = y2 = 0.0f; c = 0;
        } else {
            const float* p = x + ((size_t)b * N + idx) * ROW;
            float cx = p[0], cy = p[1], w = p[2], h = p[3];
            float hx = __fmul_rn(w, 0.5f);
            float hy = __fmul_rn(h, 0.5f);
            x1 = __fsub_rn(cx, hx); y1 = __fsub_rn(cy, hy);
            x2 = __fadd_rn(cx, hx); y2 = __fadd_rn(cy, hy);
            c = cls_id[b * N + idx];
        }
        int o = b * K + r;
        top_s[o] = s;
        boxes[o * 4 + 0] = x1; boxes[o * 4 + 1] = y1;
        boxes[o * 4 + 2] = x2; boxes[o * 4 + 3] = y2;
        clsk[o] = c;
        float sh = __fmul_rn((float)c, 4096.0f);
        float sx1 = __fadd_rn(x1, sh), sy1 = __fadd_rn(y1, sh);
        float sx2 = __fadd_rn(x2, sh), sy2 = __fadd_rn(y2, sh);
        shifted[o * 4 + 0] = sx1; shifted[o * 4 + 1] = sy1;
        shifted[o * 4 + 2] = sx2; shifted[o * 4 + 3] = sy2;
        area[o] = __fmul_rn(__fsub_rn(sx2, sx1), __fsub_rn(sy2, sy1));
    }
}

// ---------------------------------------------------------------------------
// Kernel 6: IoU bitmask + transposed diagonal blocks.
// mask[b][i][jb] bit jl: j=jb*64+jl suppressible by i (j>i, iou>0.6).
// intraT[b][c][j] bit i: within chunk c, i<j and iou(i,j)>0.6 (suppressors of j).
// ---------------------------------------------------------------------------
__global__ void nms_mask_kernel(const float* __restrict__ shifted,
                                const float* __restrict__ area,
                                unsigned long long* __restrict__ mask,
                                unsigned long long* __restrict__ intraT) {
    int jb = blockIdx.x, ib = blockIdx.y, b = blockIdx.z;
    int t = threadIdx.x;   // 0..63
    int i = ib * 64 + t;
    unsigned long long* mrow = mask + ((size_t)b * K + i) * NCHUNK + jb;
    if (jb < ib) { *mrow = 0ULL; return; }

    __shared__ float jbox[64][4];
    __shared__ float jarea[64];
    int j0 = jb * 64;
    {
        const float* sb = shifted + ((size_t)b * K + j0 + t) * 4;
        jbox[t][0] = sb[0]; jbox[t][1] = sb[1]; jbox[t][2] = sb[2]; jbox[t][3] = sb[3];
        jarea[t] = area[b * K + j0 + t];
    }
    __syncthreads();

    const float* ab = shifted + ((size_t)b * K + i) * 4;
    float ax1 = ab[0], ay1 = ab[1], ax2 = ab[2], ay2 = ab[3];
    float aarea = area[b * K + i];

    bool diag = (jb == ib);
    unsigned long long bits = 0ULL;
    unsigned long long mycol = 0ULL;
    for (int jl = 0; jl < 64; ++jl) {
        int j = j0 + jl;
        bool cond = false;
        if (j > i) {
            float lx = fmaxf(ax1, jbox[jl][0]);
            float ly = fmaxf(ay1, jbox[jl][1]);
            float rx = fminf(ax2, jbox[jl][2]);
            float ry = fminf(ay2, jbox[jl][3]);
            float w = fmaxf(__fsub_rn(rx, lx), 0.0f);
            float h = fmaxf(__fsub_rn(ry, ly), 0.0f);
            float inter = __fmul_rn(w, h);
            float denom = __fadd_rn(__fsub_rn(__fadd_rn(aarea, jarea[jl]), inter), 1e-9f);
            float iou = __fdiv_rn(inter, denom);
            cond = iou > 0.6f;
            if (cond) bits |= (1ULL << jl);
        }
        if (diag) {
            unsigned long long colm = __ballot(cond);   // bits over i for column jl
            if (t == jl) mycol = colm;
        }
    }
    *mrow = bits;
    if (diag) intraT[((size_t)b * NCHUNK + ib) * 64 + t] = mycol;
}

// ---------------------------------------------------------------------------
// Kernel 7: chunked greedy reduce. One 256-thread block per batch.
// Wave 0 resolves chunk-by-chunk (ballot fixpoint on transposed intra masks,
// removed-state OR from LDS-staged mask rows); waves 0-3 double-buffer
// prefetch the next chunk's 16 KB of mask rows.
// ---------------------------------------------------------------------------
__global__ void __launch_bounds__(256)
nms_reduce_kernel(const unsigned long long* __restrict__ mask,
                  const unsigned long long* __restrict__ intraT,
                  const float* __restrict__ top_s,
                  unsigned long long* __restrict__ keepw) {
    int b = blockIdx.x;
    int t = threadIdx.x, wv = t >> 6, ln = t & 63;
    __shared__ unsigned long long lmask[2][64 * NCHUNK];   // 2 x 16 KB
    __shared__ unsigned long long lintra[NCHUNK * 64];     // 16 KB
    __shared__ unsigned long long lvalid[NCHUNK];
    __shared__ unsigned long long lkept[NCHUNK];
    __shared__ unsigned long long lremoved[NCHUNK];

    for (int c = wv; c < NCHUNK; c += 4) {
        bool v = top_s[b * K + c * 64 + ln] > 0.0f;
        unsigned long long m = __ballot(v);
        if (ln == 0) lvalid[c] = m;
    }
    if (t < NCHUNK) lremoved[t] = 0ULL;
    {
        const ulonglong2* src = (const ulonglong2*)(intraT + (size_t)b * NCHUNK * 64);
        ulonglong2* dst = (ulonglong2*)lintra;
        for (int k = t; k < NCHUNK * 32; k += 256) dst[k] = src[k];
    }
    {
        const ulonglong2* src = (const ulonglong2*)(mask + (size_t)b * K * NCHUNK);
        ulonglong2* dst = (ulonglong2*)lmask[0];
        for (int k = t; k < 64 * NCHUNK / 2; k += 256) dst[k] = src[k];
    }
    __syncthreads();

    for (int c = 0; c < NCHUNK; ++c) {
        if (c + 1 < NCHUNK) {   // prefetch next chunk (all waves)
            const ulonglong2* src = (const ulonglong2*)(mask + ((size_t)b * K + (c + 1) * 64) * NCHUNK);
            ulonglong2* dst = (ulonglong2*)lmask[(c + 1) & 1];
            for (int k = t; k < 64 * NCHUNK / 2; k += 256) dst[k] = src[k];
        }
        if (wv == 0) {
            unsigned long long col = lintra[c * 64 + ln];     // suppressors of box ln (i<ln bits)
            unsigned long long removed_c = lremoved[c];
            unsigned long long valid = lvalid[c];
            bool undecided = (((valid >> ln) & 1ULL) != 0ULL) && (((removed_c >> ln) & 1ULL) == 0ULL);
            unsigned long long Kept = 0ULL;
            unsigned long long U = __ballot(undecided);
            while (U) {
                // resolvable: all suppressors finalized before this round
                bool resolvable = undecided && ((col & U) == 0ULL);
                bool iskept = resolvable && ((col & Kept) == 0ULL);
                unsigned long long newk = __ballot(iskept);
                unsigned long long res = __ballot(resolvable);
                Kept |= newk;
                undecided = undecided && !resolvable;
                U &= ~res;
            }
            if (ln == 0) lkept[c] = Kept;
            // cross-chunk removed accumulation: lane = half*32 + w
            int w = ln & 31, half = ln >> 5;
            unsigned long long acc = 0ULL;
            const unsigned long long* mbuf = lmask[c & 1];
            #pragma unroll 4
            for (int r = 0; r < 32; ++r) {
                int i = half * 32 + r;
                unsigned long long mm = mbuf[i * NCHUNK + w];
                acc |= ((Kept >> i) & 1ULL) ? mm : 0ULL;
            }
            acc |= __shfl(acc, ln ^ 32);
            if (half == 0) lremoved[w] |= acc;
        }
        __syncthreads();
    }
    if (t < NCHUNK) keepw[b * NCHUNK + t] = lkept[t];
}

// ---------------------------------------------------------------------------
// Kernel 8: final top-300 + output write. One wave per batch.
// ---------------------------------------------------------------------------
__global__ void nms_out_kernel(const unsigned long long* __restrict__ keepw,
                               const float* __restrict__ top_s,
                               const float* __restrict__ boxes,
                               const int* __restrict__ clsk,
                               float* __restrict__ out) {
    int b = blockIdx.x;
    int lane = threadIdx.x;   // 0..63
    int total = 0;
    for (int c = 0; c < K / 64; ++c) {
        bool k = ((keepw[b * NCHUNK + c] >> lane) & 1ULL) != 0ULL;
        unsigned long long m = __ballot(k);
        total += __popcll(m);
    }
    float* dets  = out + (size_t)b * MAXDET * 6;
    float* flags = out + (size_t)B * MAXDET * 6 + (size_t)b * MAXDET;
    unsigned long long below = (lane == 0) ? 0ULL : (~0ULL >> (64 - lane));
    int kc = 0, nc = 0;
    for (int c = 0; c < K / 64; ++c) {
        int i = c * 64 + lane;
        bool k = ((keepw[b * NCHUNK + c] >> lane) & 1ULL) != 0ULL;
        unsigned long long m = __ballot(k);
        int pc = __popcll(m);
        int slot = k ? (kc + __popcll(m & below))
                     : (total + nc + __popcll((~m) & below));
        if (slot < MAXDET) {
            int o = b * K + i;
            dets[slot * 6 + 0] = boxes[o * 4 + 0];
            dets[slot * 6 + 1] = boxes[o * 4 + 1];
            dets[slot * 6 + 2] = boxes[o * 4 + 2];
            dets[slot * 6 + 3] = boxes[o * 4 + 3];
            dets[slot * 6 + 4] = top_s[o];
            dets[slot * 6 + 5] = (float)clsk[o];
            flags[slot] = k ? 1.0f : 0.0f;
        }
        kc += pc;
        nc += 64 - pc;
    }
}

// ---------------------------------------------------------------------------
extern "C" void kernel_launch(void* const* d_in, const int* in_sizes, int n_in,
                              void* d_out, int out_size, void* d_ws, size_t ws_size,
                              hipStream_t stream) {
    const float* x = (const float*)d_in[0];
    float* out = (float*)d_out;

    char* ws = (char*)d_ws;
    size_t off = 0;
    auto alloc = [&](size_t bytes) -> void* {
        void* p = ws + off;
        off += bytes;
        off = (off + 255) & ~(size_t)255;
        return p;
    };

    float*    scores = (float*)    alloc((size_t)B * N * 4);
    int*      cls_id = (int*)      alloc((size_t)B * N * 4);
    unsigned* hist   = (unsigned*) alloc((size_t)B * NBUCKET * 4);
    unsigned* cnt    = (unsigned*) alloc((size_t)B * 4);
    int*      thresh = (int*)      alloc((size_t)B * 4);
    float*    cand_s = (float*)    alloc((size_t)B * CAND_CAP * 4);
    int*      cand_i = (int*)      alloc((size_t)B * CAND_CAP * 4);
    float*    top_s  = (float*)    alloc((size_t)B * K * 4);
    float*    boxes  = (float*)    alloc((size_t)B * K * 4 * 4);
    int*      clsk   = (int*)      alloc((size_t)B * K * 4);
    float*    shifted= (float*)    alloc((size_t)B * K * 4 * 4);
    float*    area   = (float*)    alloc((size_t)B * K * 4);
    unsigned long long* mask   = (unsigned long long*) alloc((size_t)B * K * NCHUNK * 8);
    unsigned long long* intraT = (unsigned long long*) alloc((size_t)B * NCHUNK * 64 * 8);
    unsigned long long* keepw  = (unsigned long long*) alloc((size_t)B * NCHUNK * 8);
    (void)ws_size; // needs ~7.6 MB

    int nb = (B * N + 255) / 256;
    nms_zero_kernel<<<(B * NBUCKET + 255) / 256, 256, 0, stream>>>(hist, cnt);
    nms_score_kernel<<<nb, 256, 0, stream>>>(x, scores, cls_id, hist);
    nms_thresh_kernel<<<B, 256, 0, stream>>>(hist, thresh);
    nms_compact_kernel<<<nb, 256, 0, stream>>>(scores, thresh, cnt, cand_s, cand_i);
    nms_sort_gather_kernel<<<B, 1024, 0, stream>>>(cand_s, cand_i, cnt, x, cls_id,
                                                   top_s, boxes, clsk, shifted, area);
    nms_mask_kernel<<<dim3(NCHUNK, NCHUNK, B), 64, 0, stream>>>(shifted, area, mask, intraT);
    nms_reduce_kernel<<<B, 256, 0, stream>>>(mask, intraT, top_s, keepw);
    nms_out_kernel<<<B, 64, 0, stream>>>(keepw, top_s, boxes, clsk, out);
}

// Round 3
// 304.826 us; speedup vs baseline: 3.8915x; 1.5990x over previous
//
#include <hip/hip_runtime.h>
#include <hip/hip_bf16.h>

#define B 8
#define N 25200
#define ROW 85
#define NC 80
#define K 2048
#define MAXDET 300
#define NBUCKET 16384
#define CAND_CAP 4096
#define NCHUNK 32   /* K/64 */
#define CNT_STRIDE 16  /* one counter per 64B line */

// ---------------------------------------------------------------------------
// Kernel 1: zero histogram + candidate counters (ws is poisoned 0xAA each call)
// ---------------------------------------------------------------------------
__global__ void nms_zero_kernel(unsigned* __restrict__ hist, unsigned* __restrict__ cnt) {
    int t = blockIdx.x * blockDim.x + threadIdx.x;
    if (t < B * NBUCKET) hist[t] = 0u;
    if (t < B * CNT_STRIDE) cnt[t] = 0u;
}

// ---------------------------------------------------------------------------
// Kernel 2: per-box score/cls/validity + histogram of quantized scores
// ---------------------------------------------------------------------------
__global__ void nms_score_kernel(const float* __restrict__ x,
                                 float* __restrict__ scores,
                                 int* __restrict__ cls_id,
                                 unsigned* __restrict__ hist) {
    int t = blockIdx.x * blockDim.x + threadIdx.x;
    if (t >= B * N) return;
    int b = t / N;
    const float* p = x + (size_t)t * ROW;
    float obj = p[4];
    float score = -1.0f;
    int cid = 0;
    if (obj > 0.3f) {
        float best = -1e30f;
        int bi = 0;
        #pragma unroll 8
        for (int c = 0; c < NC; ++c) {
            float v = __fmul_rn(p[5 + c], obj);   // exact, no FMA possible
            if (v > best) { best = v; bi = c; }   // first-max = np.argmax
        }
        cid = bi;
        if (best > 0.3f) {
            score = best;
            int q = (int)(__fmul_rn(best, 16384.0f));
            if (q > NBUCKET - 1) q = NBUCKET - 1;
            atomicAdd(&hist[b * NBUCKET + q], 1u);
        }
    }
    scores[t] = score;
    cls_id[t] = cid;
}

// ---------------------------------------------------------------------------
// Kernel 3: threshold bucket per batch. One block per batch; histogram staged
// in LDS; two-level descending scan (256 group sums -> refine in group).
// ---------------------------------------------------------------------------
__global__ void __launch_bounds__(256)
nms_thresh_kernel(const unsigned* __restrict__ hist, int* __restrict__ thresh) {
    int b = blockIdx.x;
    int t = threadIdx.x, ln = t & 63, wv = t >> 6;
    __shared__ unsigned lh[NBUCKET];     // 64 KB
    __shared__ unsigned gsum[256];
    const uint4* src = (const uint4*)(hist + b * NBUCKET);
    uint4* dst = (uint4*)lh;
    for (int k = t; k < NBUCKET / 4; k += 256) dst[k] = src[k];
    __syncthreads();
    // group sums (rotated LDS reads -> 2-way conflicts only)
    unsigned s = 0;
    for (int k = 0; k < 64; ++k) s += lh[t * 64 + ((k + t) & 63)];
    gsum[t] = s;
    __syncthreads();
    if (wv == 0) {
        int cum = 0, found_g = -1, base_for_g = 0;
        for (int r = 0; r < 4 && found_g < 0; ++r) {
            int g = 255 - (r * 64 + ln);            // descending group order
            unsigned v = gsum[g];
            unsigned pref = v;
            #pragma unroll
            for (int o = 1; o < 64; o <<= 1) { unsigned u = __shfl_up(pref, o, 64); if (ln >= o) pref += u; }
            unsigned total = __shfl(pref, 63, 64);
            if (cum + (int)total >= K) {
                bool hit = (cum + (int)pref) >= K;
                unsigned long long m = __ballot(hit);
                int fl = __ffsll(m) - 1;
                found_g = 255 - (r * 64 + fl);
                unsigned pf = __shfl(pref, fl, 64);
                unsigned vv = __shfl(v, fl, 64);
                base_for_g = cum + (int)pf - (int)vv;  // cumulative above found group
            }
            cum += (int)total;
        }
        int T = 0;
        if (found_g >= 0) {
            int q = found_g * 64 + 63 - ln;          // descending bucket order
            unsigned v = lh[q];
            unsigned pref = v;
            #pragma unroll
            for (int o = 1; o < 64; o <<= 1) { unsigned u = __shfl_up(pref, o, 64); if (ln >= o) pref += u; }
            bool hit = (base_for_g + (int)pref) >= K;
            unsigned long long m = __ballot(hit);
            int fl = __ffsll(m) - 1;
            T = (fl >= 0) ? (found_g * 64 + 63 - fl) : 0;
        }
        if (ln == 0) thresh[b] = T;
    }
}

// ---------------------------------------------------------------------------
// Kernel 4: compact candidates. Hierarchical allocation: LDS counter per
// block -> ONE global atomic per block (792 total, 64B-strided counters).
// Order within cand_* is arbitrary; kernel 5 fully sorts (score desc, idx asc)
// so the final result is unchanged.
// ---------------------------------------------------------------------------
__global__ void __launch_bounds__(256)
nms_compact_kernel(const float* __restrict__ scores,
                   const int* __restrict__ thresh,
                   unsigned* __restrict__ cnt,
                   float* __restrict__ cand_s,
                   int* __restrict__ cand_i) {
    int b = blockIdx.y;
    int i = blockIdx.x * 256 + threadIdx.x;
    __shared__ unsigned lcnt, gbase;
    if (threadIdx.x == 0) lcnt = 0u;
    __syncthreads();
    float s = -1.0f;
    unsigned mypos = 0u;
    bool cand = false;
    if (i < N) {
        s = scores[b * N + i];
        if (s > 0.0f) {
            int q = (int)(__fmul_rn(s, 16384.0f));
            if (q > NBUCKET - 1) q = NBUCKET - 1;
            if (q >= thresh[b]) { cand = true; mypos = atomicAdd(&lcnt, 1u); }
        }
    }
    __syncthreads();
    if (threadIdx.x == 0) gbase = atomicAdd(&cnt[b * CNT_STRIDE], lcnt);
    __syncthreads();
    if (cand) {
        unsigned pos = gbase + mypos;
        if (pos < CAND_CAP) {
            cand_s[b * CAND_CAP + pos] = s;
            cand_i[b * CAND_CAP + pos] = i;
        }
    }
}

// ---------------------------------------------------------------------------
// Kernel 5: bitonic sort 4096 candidates in LDS (desc score, asc idx),
//           gather top-2048 boxes / cls / shifted boxes / areas
// ---------------------------------------------------------------------------
__global__ void __launch_bounds__(1024)
nms_sort_gather_kernel(const float* __restrict__ cand_s,
                       const int* __restrict__ cand_i,
                       const unsigned* __restrict__ cnt,
                       const float* __restrict__ x,
                       const int* __restrict__ cls_id,
                       float* __restrict__ top_s,
                       float* __restrict__ boxes,
                       int* __restrict__ clsk,
                       float* __restrict__ shifted,
                       float* __restrict__ area) {
    __shared__ float ss[CAND_CAP];
    __shared__ int   si[CAND_CAP];
    int b = blockIdx.x;
    unsigned n = cnt[b * CNT_STRIDE];
    if (n > CAND_CAP) n = CAND_CAP;
    for (int i = threadIdx.x; i < CAND_CAP; i += 1024) {
        if (i < (int)n) { ss[i] = cand_s[b * CAND_CAP + i]; si[i] = cand_i[b * CAND_CAP + i]; }
        else            { ss[i] = -1e30f; si[i] = 0x7FFFFFFF; }
    }
    __syncthreads();
    for (int k = 2; k <= CAND_CAP; k <<= 1) {
        for (int j = k >> 1; j > 0; j >>= 1) {
            for (int i = threadIdx.x; i < CAND_CAP; i += 1024) {
                int p = i ^ j;
                if (p > i) {
                    float s1 = ss[i], s2 = ss[p];
                    int   i1 = si[i], i2 = si[p];
                    bool inOrder = (s1 > s2) || (s1 == s2 && i1 <= i2);
                    bool dirBestFirst = ((i & k) == 0);
                    bool doSwap = dirBestFirst ? (!inOrder) : inOrder;
                    if (doSwap) { ss[i] = s2; si[i] = i2; ss[p] = s1; si[p] = i1; }
                }
            }
            __syncthreads();
        }
    }
    for (int r = threadIdx.x; r < K; r += 1024) {
        float s = ss[r];
        int idx = si[r];
        float x1, y1, x2, y2;
        int c;
        if (idx == 0x7FFFFFFF) {
            s = -1.0f; x1 = y1 = x2 = y2 = 0.0f; c = 0;
        } else {
            const float* p = x + ((size_t)b * N + idx) * ROW;
            float cx = p[0], cy = p[1], w = p[2], h = p[3];
            float hx = __fmul_rn(w, 0.5f);
            float hy = __fmul_rn(h, 0.5f);
            x1 = __fsub_rn(cx, hx); y1 = __fsub_rn(cy, hy);
            x2 = __fadd_rn(cx, hx); y2 = __fadd_rn(cy, hy);
            c = cls_id[b * N + idx];
        }
        int o = b * K + r;
        top_s[o] = s;
        boxes[o * 4 + 0] = x1; boxes[o * 4 + 1] = y1;
        boxes[o * 4 + 2] = x2; boxes[o * 4 + 3] = y2;
        clsk[o] = c;
        float sh = __fmul_rn((float)c, 4096.0f);
        float sx1 = __fadd_rn(x1, sh), sy1 = __fadd_rn(y1, sh);
        float sx2 = __fadd_rn(x2, sh), sy2 = __fadd_rn(y2, sh);
        shifted[o * 4 + 0] = sx1; shifted[o * 4 + 1] = sy1;
        shifted[o * 4 + 2] = sx2; shifted[o * 4 + 3] = sy2;
        area[o] = __fmul_rn(__fsub_rn(sx2, sx1), __fsub_rn(sy2, sy1));
    }
}

// ---------------------------------------------------------------------------
// Kernel 6: IoU bitmask + transposed diagonal blocks.
// mask[b][i][jb] bit jl: j=jb*64+jl suppressible by i (j>i, iou>0.6).
// intraT[b][c][j] bit i: within chunk c, i<j and iou(i,j)>0.6 (suppressors of j).
// ---------------------------------------------------------------------------
__global__ void nms_mask_kernel(const float* __restrict__ shifted,
                                const float* __restrict__ area,
                                unsigned long long* __restrict__ mask,
                                unsigned long long* __restrict__ intraT) {
    int jb = blockIdx.x, ib = blockIdx.y, b = blockIdx.z;
    int t = threadIdx.x;   // 0..63
    int i = ib * 64 + t;
    unsigned long long* mrow = mask + ((size_t)b * K + i) * NCHUNK + jb;
    if (jb < ib) { *mrow = 0ULL; return; }

    __shared__ float jbox[64][4];
    __shared__ float jarea[64];
    int j0 = jb * 64;
    {
        const float* sb = shifted + ((size_t)b * K + j0 + t) * 4;
        jbox[t][0] = sb[0]; jbox[t][1] = sb[1]; jbox[t][2] = sb[2]; jbox[t][3] = sb[3];
        jarea[t] = area[b * K + j0 + t];
    }
    __syncthreads();

    const float* ab = shifted + ((size_t)b * K + i) * 4;
    float ax1 = ab[0], ay1 = ab[1], ax2 = ab[2], ay2 = ab[3];
    float aarea = area[b * K + i];

    bool diag = (jb == ib);
    unsigned long long bits = 0ULL;
    unsigned long long mycol = 0ULL;
    for (int jl = 0; jl < 64; ++jl) {
        int j = j0 + jl;
        bool cond = false;
        if (j > i) {
            float lx = fmaxf(ax1, jbox[jl][0]);
            float ly = fmaxf(ay1, jbox[jl][1]);
            float rx = fminf(ax2, jbox[jl][2]);
            float ry = fminf(ay2, jbox[jl][3]);
            float w = fmaxf(__fsub_rn(rx, lx), 0.0f);
            float h = fmaxf(__fsub_rn(ry, ly), 0.0f);
            float inter = __fmul_rn(w, h);
            float denom = __fadd_rn(__fsub_rn(__fadd_rn(aarea, jarea[jl]), inter), 1e-9f);
            float iou = __fdiv_rn(inter, denom);
            cond = iou > 0.6f;
            if (cond) bits |= (1ULL << jl);
        }
        if (diag) {
            unsigned long long colm = __ballot(cond);   // bits over i for column jl
            if (t == jl) mycol = colm;
        }
    }
    *mrow = bits;
    if (diag) intraT[((size_t)b * NCHUNK + ib) * 64 + t] = mycol;
}

// ---------------------------------------------------------------------------
// Kernel 7: chunked greedy reduce. One 256-thread block per batch.
// ---------------------------------------------------------------------------
__global__ void __launch_bounds__(256)
nms_reduce_kernel(const unsigned long long* __restrict__ mask,
                  const unsigned long long* __restrict__ intraT,
                  const float* __restrict__ top_s,
                  unsigned long long* __restrict__ keepw) {
    int b = blockIdx.x;
    int t = threadIdx.x, wv = t >> 6, ln = t & 63;
    __shared__ unsigned long long lmask[2][64 * NCHUNK];   // 2 x 16 KB
    __shared__ unsigned long long lintra[NCHUNK * 64];     // 16 KB
    __shared__ unsigned long long lvalid[NCHUNK];
    __shared__ unsigned long long lkept[NCHUNK];
    __shared__ unsigned long long lremoved[NCHUNK];

    for (int c = wv; c < NCHUNK; c += 4) {
        bool v = top_s[b * K + c * 64 + ln] > 0.0f;
        unsigned long long m = __ballot(v);
        if (ln == 0) lvalid[c] = m;
    }
    if (t < NCHUNK) lremoved[t] = 0ULL;
    {
        const ulonglong2* src = (const ulonglong2*)(intraT + (size_t)b * NCHUNK * 64);
        ulonglong2* dst = (ulonglong2*)lintra;
        for (int k = t; k < NCHUNK * 32; k += 256) dst[k] = src[k];
    }
    {
        const ulonglong2* src = (const ulonglong2*)(mask + (size_t)b * K * NCHUNK);
        ulonglong2* dst = (ulonglong2*)lmask[0];
        for (int k = t; k < 64 * NCHUNK / 2; k += 256) dst[k] = src[k];
    }
    __syncthreads();

    for (int c = 0; c < NCHUNK; ++c) {
        if (c + 1 < NCHUNK) {   // prefetch next chunk (all waves)
            const ulonglong2* src = (const ulonglong2*)(mask + ((size_t)b * K + (c + 1) * 64) * NCHUNK);
            ulonglong2* dst = (ulonglong2*)lmask[(c + 1) & 1];
            for (int k = t; k < 64 * NCHUNK / 2; k += 256) dst[k] = src[k];
        }
        if (wv == 0) {
            unsigned long long col = lintra[c * 64 + ln];     // suppressors of box ln (i<ln bits)
            unsigned long long removed_c = lremoved[c];
            unsigned long long valid = lvalid[c];
            bool undecided = (((valid >> ln) & 1ULL) != 0ULL) && (((removed_c >> ln) & 1ULL) == 0ULL);
            unsigned long long Kept = 0ULL;
            unsigned long long U = __ballot(undecided);
            while (U) {
                bool resolvable = undecided && ((col & U) == 0ULL);
                bool iskept = resolvable && ((col & Kept) == 0ULL);
                unsigned long long newk = __ballot(iskept);
                unsigned long long res = __ballot(resolvable);
                Kept |= newk;
                undecided = undecided && !resolvable;
                U &= ~res;
            }
            if (ln == 0) lkept[c] = Kept;
            int w = ln & 31, half = ln >> 5;
            unsigned long long acc = 0ULL;
            const unsigned long long* mbuf = lmask[c & 1];
            #pragma unroll 4
            for (int r = 0; r < 32; ++r) {
                int i = half * 32 + r;
                unsigned long long mm = mbuf[i * NCHUNK + w];
                acc |= ((Kept >> i) & 1ULL) ? mm : 0ULL;
            }
            acc |= __shfl(acc, ln ^ 32);
            if (half == 0) lremoved[w] |= acc;
        }
        __syncthreads();
    }
    if (t < NCHUNK) keepw[b * NCHUNK + t] = lkept[t];
}

// ---------------------------------------------------------------------------
// Kernel 8: final top-300 + output write. One wave per batch.
// ---------------------------------------------------------------------------
__global__ void nms_out_kernel(const unsigned long long* __restrict__ keepw,
                               const float* __restrict__ top_s,
                               const float* __restrict__ boxes,
                               const int* __restrict__ clsk,
                               float* __restrict__ out) {
    int b = blockIdx.x;
    int lane = threadIdx.x;   // 0..63
    int total = 0;
    for (int c = 0; c < K / 64; ++c) {
        bool k = ((keepw[b * NCHUNK + c] >> lane) & 1ULL) != 0ULL;
        unsigned long long m = __ballot(k);
        total += __popcll(m);
    }
    float* dets  = out + (size_t)b * MAXDET * 6;
    float* flags = out + (size_t)B * MAXDET * 6 + (size_t)b * MAXDET;
    unsigned long long below = (lane == 0) ? 0ULL : (~0ULL >> (64 - lane));
    int kc = 0, nc = 0;
    for (int c = 0; c < K / 64; ++c) {
        int i = c * 64 + lane;
        bool k = ((keepw[b * NCHUNK + c] >> lane) & 1ULL) != 0ULL;
        unsigned long long m = __ballot(k);
        int pc = __popcll(m);
        int slot = k ? (kc + __popcll(m & below))
                     : (total + nc + __popcll((~m) & below));
        if (slot < MAXDET) {
            int o = b * K + i;
            dets[slot * 6 + 0] = boxes[o * 4 + 0];
            dets[slot * 6 + 1] = boxes[o * 4 + 1];
            dets[slot * 6 + 2] = boxes[o * 4 + 2];
            dets[slot * 6 + 3] = boxes[o * 4 + 3];
            dets[slot * 6 + 4] = top_s[o];
            dets[slot * 6 + 5] = (float)clsk[o];
            flags[slot] = k ? 1.0f : 0.0f;
        }
        kc += pc;
        nc += 64 - pc;
    }
}

// ---------------------------------------------------------------------------
extern "C" void kernel_launch(void* const* d_in, const int* in_sizes, int n_in,
                              void* d_out, int out_size, void* d_ws, size_t ws_size,
                              hipStream_t stream) {
    const float* x = (const float*)d_in[0];
    float* out = (float*)d_out;

    char* ws = (char*)d_ws;
    size_t off = 0;
    auto alloc = [&](size_t bytes) -> void* {
        void* p = ws + off;
        off += bytes;
        off = (off + 255) & ~(size_t)255;
        return p;
    };

    float*    scores = (float*)    alloc((size_t)B * N * 4);
    int*      cls_id = (int*)      alloc((size_t)B * N * 4);
    unsigned* hist   = (unsigned*) alloc((size_t)B * NBUCKET * 4);
    unsigned* cnt    = (unsigned*) alloc((size_t)B * CNT_STRIDE * 4);
    int*      thresh = (int*)      alloc((size_t)B * 4);
    float*    cand_s = (float*)    alloc((size_t)B * CAND_CAP * 4);
    int*      cand_i = (int*)      alloc((size_t)B * CAND_CAP * 4);
    float*    top_s  = (float*)    alloc((size_t)B * K * 4);
    float*    boxes  = (float*)    alloc((size_t)B * K * 4 * 4);
    int*      clsk   = (int*)      alloc((size_t)B * K * 4);
    float*    shifted= (float*)    alloc((size_t)B * K * 4 * 4);
    float*    area   = (float*)    alloc((size_t)B * K * 4);
    unsigned long long* mask   = (unsigned long long*) alloc((size_t)B * K * NCHUNK * 8);
    unsigned long long* intraT = (unsigned long long*) alloc((size_t)B * NCHUNK * 64 * 8);
    unsigned long long* keepw  = (unsigned long long*) alloc((size_t)B * NCHUNK * 8);
    (void)ws_size; // needs ~7.6 MB

    int nb = (B * N + 255) / 256;
    nms_zero_kernel<<<(B * NBUCKET + 255) / 256, 256, 0, stream>>>(hist, cnt);
    nms_score_kernel<<<nb, 256, 0, stream>>>(x, scores, cls_id, hist);
    nms_thresh_kernel<<<B, 256, 0, stream>>>(hist, thresh);
    nms_compact_kernel<<<dim3((N + 255) / 256, B), 256, 0, stream>>>(scores, thresh, cnt, cand_s, cand_i);
    nms_sort_gather_kernel<<<B, 1024, 0, stream>>>(cand_s, cand_i, cnt, x, cls_id,
                                                   top_s, boxes, clsk, shifted, area);
    nms_mask_kernel<<<dim3(NCHUNK, NCHUNK, B), 64, 0, stream>>>(shifted, area, mask, intraT);
    nms_reduce_kernel<<<B, 256, 0, stream>>>(mask, intraT, top_s, keepw);
    nms_out_kernel<<<B, 64, 0, stream>>>(keepw, top_s, boxes, clsk, out);
}

// Round 4
// 248.565 us; speedup vs baseline: 4.7723x; 1.2263x over previous
//
#include <hip/hip_runtime.h>
#include <hip/hip_bf16.h>

#define B 8
#define N 25200
#define ROW 85
#define NC 80
#define K 2048
#define MAXDET 300
#define NBUCKET 16384
#define CAND_CAP 4096
#define NCHUNK 32   /* K/64 */

// ---------------------------------------------------------------------------
// Kernel 1: zero histogram (ws is poisoned 0xAA each call)
// ---------------------------------------------------------------------------
__global__ void nms_zero_kernel(unsigned* __restrict__ hist) {
    int t = blockIdx.x * blockDim.x + threadIdx.x;
    if (t < B * NBUCKET) hist[t] = 0u;
}

// ---------------------------------------------------------------------------
// Kernel 2: per-box score/cls/validity + histogram of quantized scores
// ---------------------------------------------------------------------------
__global__ void nms_score_kernel(const float* __restrict__ x,
                                 float* __restrict__ scores,
                                 int* __restrict__ cls_id,
                                 unsigned* __restrict__ hist) {
    int t = blockIdx.x * blockDim.x + threadIdx.x;
    if (t >= B * N) return;
    int b = t / N;
    const float* p = x + (size_t)t * ROW;
    float obj = p[4];
    float score = -1.0f;
    int cid = 0;
    if (obj > 0.3f) {
        float best = -1e30f;
        int bi = 0;
        #pragma unroll 8
        for (int c = 0; c < NC; ++c) {
            float v = __fmul_rn(p[5 + c], obj);   // exact, no FMA possible
            if (v > best) { best = v; bi = c; }   // first-max = np.argmax
        }
        cid = bi;
        if (best > 0.3f) {
            score = best;
            int q = (int)(__fmul_rn(best, 16384.0f));
            if (q > NBUCKET - 1) q = NBUCKET - 1;
            atomicAdd(&hist[b * NBUCKET + q], 1u);
        }
    }
    scores[t] = score;
    cls_id[t] = cid;
}

// ---------------------------------------------------------------------------
// Kernel 3 (fused select): counting sort by histogram rank.
//  - LDS descending exclusive scan of 16384-bucket histogram -> exact bucket
//    start ranks loff[q].
//  - Placement: every valid box whose bucket starts < CAND_CAP takes slot
//    loff[q] + within-bucket-rank (packed u16 LDS atomic cursors) and writes
//    key = (score_bits<<32) | ~idx  (desc u64 == score desc, idx asc).
//  - Per-bucket insertion sort (disjoint ranges, one pass, no barrier loop).
//  - Gather top-K boxes/cls/shifted/area.
// LDS: 64KB loff + 32KB cursors + 32KB keys = 128KB -> 1 block/CU (8 blocks).
// ---------------------------------------------------------------------------
__global__ void __launch_bounds__(1024, 1)
nms_select_kernel(const unsigned* __restrict__ hist,
                  const float* __restrict__ scores,
                  const float* __restrict__ x,
                  const int* __restrict__ cls_id,
                  float* __restrict__ top_s,
                  float* __restrict__ boxes,
                  int* __restrict__ clsk,
                  float* __restrict__ shifted,
                  float* __restrict__ area) {
    __shared__ unsigned loff[NBUCKET];          // 64 KB: hist -> start ranks
    __shared__ unsigned lcnt16[NBUCKET / 2];    // 32 KB: packed u16 cursors
    __shared__ unsigned long long lk[CAND_CAP]; // 32 KB: packed sort keys
    __shared__ unsigned wsum[16];

    int b = blockIdx.x;
    int t = threadIdx.x;
    int ln = t & 63, wv = t >> 6;

    // stage histogram, clear cursors + keys
    {
        const uint4* src = (const uint4*)(hist + b * NBUCKET);
        uint4* dst = (uint4*)loff;
        for (int k = t; k < NBUCKET / 4; k += 1024) dst[k] = src[k];
    }
    for (int k = t; k < NBUCKET / 2; k += 1024) lcnt16[k] = 0u;
    for (int k = t; k < CAND_CAP; k += 1024) lk[k] = 0ULL;
    __syncthreads();

    // descending exclusive scan: loff[q] = sum of hist[q'] for q' > q
    unsigned v[16];
    unsigned S = 0;
    int base_j = t * 16;
    #pragma unroll
    for (int k = 0; k < 16; ++k) { v[k] = loff[NBUCKET - 1 - (base_j + k)]; S += v[k]; }
    unsigned pref = S;
    #pragma unroll
    for (int o = 1; o < 64; o <<= 1) { unsigned u = __shfl_up(pref, o, 64); if (ln >= o) pref += u; }
    if (ln == 63) wsum[wv] = pref;
    __syncthreads();
    unsigned wbase = 0;
    for (int w = 0; w < wv; ++w) wbase += wsum[w];   // broadcast reads
    unsigned running = wbase + pref - S;             // exclusive base for this thread
    #pragma unroll
    for (int k = 0; k < 16; ++k) {
        loff[NBUCKET - 1 - (base_j + k)] = running;
        running += v[k];
    }
    __syncthreads();

    // placement (counting sort)
    for (int i = t; i < N; i += 1024) {
        float s = scores[b * N + i];
        if (s > 0.0f) {
            int q = (int)(__fmul_rn(s, 16384.0f));
            if (q > NBUCKET - 1) q = NBUCKET - 1;
            unsigned start = loff[q];
            if (start < CAND_CAP) {
                unsigned sh = (q & 1) * 16;
                unsigned old = atomicAdd(&lcnt16[q >> 1], 1u << sh);
                unsigned rank = (old >> sh) & 0xFFFFu;
                unsigned pos = start + rank;
                if (pos < CAND_CAP) {
                    unsigned long long key =
                        ((unsigned long long)__float_as_uint(s) << 32) | (unsigned)(~i);
                    lk[pos] = key;
                }
            }
        }
    }
    __syncthreads();

    // per-bucket insertion sort (descending keys), disjoint ranges
    for (int q = t; q < NBUCKET; q += 1024) {
        unsigned start = loff[q];
        if (start < CAND_CAP) {
            unsigned c = (lcnt16[q >> 1] >> ((q & 1) * 16)) & 0xFFFFu;
            unsigned m = c;
            if (m > CAND_CAP - start) m = CAND_CAP - start;
            if (m >= 2) {
                for (unsigned a = start + 1; a < start + m; ++a) {
                    unsigned long long kv = lk[a];
                    unsigned p2 = a;
                    while (p2 > start && lk[p2 - 1] < kv) { lk[p2] = lk[p2 - 1]; --p2; }
                    lk[p2] = kv;
                }
            }
        }
    }
    __syncthreads();

    // gather top-K
    for (int r = t; r < K; r += 1024) {
        unsigned long long key = lk[r];
        float s;
        int idx;
        float x1, y1, x2, y2;
        int c;
        if (key == 0ULL) {
            s = -1.0f; x1 = y1 = x2 = y2 = 0.0f; c = 0;
        } else {
            s = __uint_as_float((unsigned)(key >> 32));
            idx = (int)(~(unsigned)key);
            const float* p = x + ((size_t)b * N + idx) * ROW;
            float cx = p[0], cy = p[1], w = p[2], h = p[3];
            float hx = __fmul_rn(w, 0.5f);
            float hy = __fmul_rn(h, 0.5f);
            x1 = __fsub_rn(cx, hx); y1 = __fsub_rn(cy, hy);
            x2 = __fadd_rn(cx, hx); y2 = __fadd_rn(cy, hy);
            c = cls_id[b * N + idx];
        }
        int o = b * K + r;
        top_s[o] = s;
        boxes[o * 4 + 0] = x1; boxes[o * 4 + 1] = y1;
        boxes[o * 4 + 2] = x2; boxes[o * 4 + 3] = y2;
        clsk[o] = c;
        float sh = __fmul_rn((float)c, 4096.0f);
        float sx1 = __fadd_rn(x1, sh), sy1 = __fadd_rn(y1, sh);
        float sx2 = __fadd_rn(x2, sh), sy2 = __fadd_rn(y2, sh);
        shifted[o * 4 + 0] = sx1; shifted[o * 4 + 1] = sy1;
        shifted[o * 4 + 2] = sx2; shifted[o * 4 + 3] = sy2;
        area[o] = __fmul_rn(__fsub_rn(sx2, sx1), __fsub_rn(sy2, sy1));
    }
}

// ---------------------------------------------------------------------------
// Kernel 4: IoU bitmask + transposed diagonal blocks.
// ---------------------------------------------------------------------------
__global__ void nms_mask_kernel(const float* __restrict__ shifted,
                                const float* __restrict__ area,
                                unsigned long long* __restrict__ mask,
                                unsigned long long* __restrict__ intraT) {
    int jb = blockIdx.x, ib = blockIdx.y, b = blockIdx.z;
    int t = threadIdx.x;   // 0..63
    int i = ib * 64 + t;
    unsigned long long* mrow = mask + ((size_t)b * K + i) * NCHUNK + jb;
    if (jb < ib) { *mrow = 0ULL; return; }

    __shared__ float jbox[64][4];
    __shared__ float jarea[64];
    int j0 = jb * 64;
    {
        const float* sb = shifted + ((size_t)b * K + j0 + t) * 4;
        jbox[t][0] = sb[0]; jbox[t][1] = sb[1]; jbox[t][2] = sb[2]; jbox[t][3] = sb[3];
        jarea[t] = area[b * K + j0 + t];
    }
    __syncthreads();

    const float* ab = shifted + ((size_t)b * K + i) * 4;
    float ax1 = ab[0], ay1 = ab[1], ax2 = ab[2], ay2 = ab[3];
    float aarea = area[b * K + i];

    bool diag = (jb == ib);
    unsigned long long bits = 0ULL;
    unsigned long long mycol = 0ULL;
    for (int jl = 0; jl < 64; ++jl) {
        int j = j0 + jl;
        bool cond = false;
        if (j > i) {
            float lx = fmaxf(ax1, jbox[jl][0]);
            float ly = fmaxf(ay1, jbox[jl][1]);
            float rx = fminf(ax2, jbox[jl][2]);
            float ry = fminf(ay2, jbox[jl][3]);
            float w = fmaxf(__fsub_rn(rx, lx), 0.0f);
            float h = fmaxf(__fsub_rn(ry, ly), 0.0f);
            float inter = __fmul_rn(w, h);
            float denom = __fadd_rn(__fsub_rn(__fadd_rn(aarea, jarea[jl]), inter), 1e-9f);
            float iou = __fdiv_rn(inter, denom);
            cond = iou > 0.6f;
            if (cond) bits |= (1ULL << jl);
        }
        if (diag) {
            unsigned long long colm = __ballot(cond);   // bits over i for column jl
            if (t == jl) mycol = colm;
        }
    }
    *mrow = bits;
    if (diag) intraT[((size_t)b * NCHUNK + ib) * 64 + t] = mycol;
}

// ---------------------------------------------------------------------------
// Kernel 5: chunked greedy reduce. One 256-thread block per batch.
// ---------------------------------------------------------------------------
__global__ void __launch_bounds__(256)
nms_reduce_kernel(const unsigned long long* __restrict__ mask,
                  const unsigned long long* __restrict__ intraT,
                  const float* __restrict__ top_s,
                  unsigned long long* __restrict__ keepw) {
    int b = blockIdx.x;
    int t = threadIdx.x, wv = t >> 6, ln = t & 63;
    __shared__ unsigned long long lmask[2][64 * NCHUNK];   // 2 x 16 KB
    __shared__ unsigned long long lintra[NCHUNK * 64];     // 16 KB
    __shared__ unsigned long long lvalid[NCHUNK];
    __shared__ unsigned long long lkept[NCHUNK];
    __shared__ unsigned long long lremoved[NCHUNK];

    for (int c = wv; c < NCHUNK; c += 4) {
        bool v = top_s[b * K + c * 64 + ln] > 0.0f;
        unsigned long long m = __ballot(v);
        if (ln == 0) lvalid[c] = m;
    }
    if (t < NCHUNK) lremoved[t] = 0ULL;
    {
        const ulonglong2* src = (const ulonglong2*)(intraT + (size_t)b * NCHUNK * 64);
        ulonglong2* dst = (ulonglong2*)lintra;
        for (int k = t; k < NCHUNK * 32; k += 256) dst[k] = src[k];
    }
    {
        const ulonglong2* src = (const ulonglong2*)(mask + (size_t)b * K * NCHUNK);
        ulonglong2* dst = (ulonglong2*)lmask[0];
        for (int k = t; k < 64 * NCHUNK / 2; k += 256) dst[k] = src[k];
    }
    __syncthreads();

    for (int c = 0; c < NCHUNK; ++c) {
        if (c + 1 < NCHUNK) {   // prefetch next chunk (all waves)
            const ulonglong2* src = (const ulonglong2*)(mask + ((size_t)b * K + (c + 1) * 64) * NCHUNK);
            ulonglong2* dst = (ulonglong2*)lmask[(c + 1) & 1];
            for (int k = t; k < 64 * NCHUNK / 2; k += 256) dst[k] = src[k];
        }
        if (wv == 0) {
            unsigned long long col = lintra[c * 64 + ln];     // suppressors of box ln
            unsigned long long removed_c = lremoved[c];
            unsigned long long valid = lvalid[c];
            bool undecided = (((valid >> ln) & 1ULL) != 0ULL) && (((removed_c >> ln) & 1ULL) == 0ULL);
            unsigned long long Kept = 0ULL;
            unsigned long long U = __ballot(undecided);
            while (U) {
                bool resolvable = undecided && ((col & U) == 0ULL);
                bool iskept = resolvable && ((col & Kept) == 0ULL);
                unsigned long long newk = __ballot(iskept);
                unsigned long long res = __ballot(resolvable);
                Kept |= newk;
                undecided = undecided && !resolvable;
                U &= ~res;
            }
            if (ln == 0) lkept[c] = Kept;
            int w = ln & 31, half = ln >> 5;
            unsigned long long acc = 0ULL;
            const unsigned long long* mbuf = lmask[c & 1];
            #pragma unroll 4
            for (int r = 0; r < 32; ++r) {
                int i = half * 32 + r;
                unsigned long long mm = mbuf[i * NCHUNK + w];
                acc |= ((Kept >> i) & 1ULL) ? mm : 0ULL;
            }
            acc |= __shfl(acc, ln ^ 32);
            if (half == 0) lremoved[w] |= acc;
        }
        __syncthreads();
    }
    if (t < NCHUNK) keepw[b * NCHUNK + t] = lkept[t];
}

// ---------------------------------------------------------------------------
// Kernel 6: final top-300 + output write. One wave per batch.
// ---------------------------------------------------------------------------
__global__ void nms_out_kernel(const unsigned long long* __restrict__ keepw,
                               const float* __restrict__ top_s,
                               const float* __restrict__ boxes,
                               const int* __restrict__ clsk,
                               float* __restrict__ out) {
    int b = blockIdx.x;
    int lane = threadIdx.x;   // 0..63
    int total = 0;
    for (int c = 0; c < K / 64; ++c) {
        bool k = ((keepw[b * NCHUNK + c] >> lane) & 1ULL) != 0ULL;
        unsigned long long m = __ballot(k);
        total += __popcll(m);
    }
    float* dets  = out + (size_t)b * MAXDET * 6;
    float* flags = out + (size_t)B * MAXDET * 6 + (size_t)b * MAXDET;
    unsigned long long below = (lane == 0) ? 0ULL : (~0ULL >> (64 - lane));
    int kc = 0, nc = 0;
    for (int c = 0; c < K / 64; ++c) {
        int i = c * 64 + lane;
        bool k = ((keepw[b * NCHUNK + c] >> lane) & 1ULL) != 0ULL;
        unsigned long long m = __ballot(k);
        int pc = __popcll(m);
        int slot = k ? (kc + __popcll(m & below))
                     : (total + nc + __popcll((~m) & below));
        if (slot < MAXDET) {
            int o = b * K + i;
            dets[slot * 6 + 0] = boxes[o * 4 + 0];
            dets[slot * 6 + 1] = boxes[o * 4 + 1];
            dets[slot * 6 + 2] = boxes[o * 4 + 2];
            dets[slot * 6 + 3] = boxes[o * 4 + 3];
            dets[slot * 6 + 4] = top_s[o];
            dets[slot * 6 + 5] = (float)clsk[o];
            flags[slot] = k ? 1.0f : 0.0f;
        }
        kc += pc;
        nc += 64 - pc;
    }
}

// ---------------------------------------------------------------------------
extern "C" void kernel_launch(void* const* d_in, const int* in_sizes, int n_in,
                              void* d_out, int out_size, void* d_ws, size_t ws_size,
                              hipStream_t stream) {
    const float* x = (const float*)d_in[0];
    float* out = (float*)d_out;

    char* ws = (char*)d_ws;
    size_t off = 0;
    auto alloc = [&](size_t bytes) -> void* {
        void* p = ws + off;
        off += bytes;
        off = (off + 255) & ~(size_t)255;
        return p;
    };

    float*    scores = (float*)    alloc((size_t)B * N * 4);
    int*      cls_id = (int*)      alloc((size_t)B * N * 4);
    unsigned* hist   = (unsigned*) alloc((size_t)B * NBUCKET * 4);
    float*    top_s  = (float*)    alloc((size_t)B * K * 4);
    float*    boxes  = (float*)    alloc((size_t)B * K * 4 * 4);
    int*      clsk   = (int*)      alloc((size_t)B * K * 4);
    float*    shifted= (float*)    alloc((size_t)B * K * 4 * 4);
    float*    area   = (float*)    alloc((size_t)B * K * 4);
    unsigned long long* mask   = (unsigned long long*) alloc((size_t)B * K * NCHUNK * 8);
    unsigned long long* intraT = (unsigned long long*) alloc((size_t)B * NCHUNK * 64 * 8);
    unsigned long long* keepw  = (unsigned long long*) alloc((size_t)B * NCHUNK * 8);
    (void)ws_size; // needs ~7.5 MB

    int nb = (B * N + 255) / 256;
    nms_zero_kernel<<<(B * NBUCKET + 255) / 256, 256, 0, stream>>>(hist);
    nms_score_kernel<<<nb, 256, 0, stream>>>(x, scores, cls_id, hist);
    nms_select_kernel<<<B, 1024, 0, stream>>>(hist, scores, x, cls_id,
                                              top_s, boxes, clsk, shifted, area);
    nms_mask_kernel<<<dim3(NCHUNK, NCHUNK, B), 64, 0, stream>>>(shifted, area, mask, intraT);
    nms_reduce_kernel<<<B, 256, 0, stream>>>(mask, intraT, top_s, keepw);
    nms_out_kernel<<<B, 64, 0, stream>>>(keepw, top_s, boxes, clsk, out);
}

// Round 5
// 185.712 us; speedup vs baseline: 6.3875x; 1.3384x over previous
//
#include <hip/hip_runtime.h>
#include <hip/hip_bf16.h>

#define B 8
#define N 25200
#define ROW 85
#define NC 80
#define K 2048
#define MAXDET 300
#define NBUCKET 16384
#define CAND_CAP 4096
#define NCHUNK 32   /* K/64 */

// ---------------------------------------------------------------------------
// Kernel 1: zero histogram (ws is poisoned 0xAA each call)
// ---------------------------------------------------------------------------
__global__ void nms_zero_kernel(unsigned* __restrict__ hist) {
    int t = blockIdx.x * blockDim.x + threadIdx.x;
    if (t < B * NBUCKET) hist[t] = 0u;
}

// ---------------------------------------------------------------------------
// Kernel 2: per-box score/cls/validity + histogram. 4 lanes per box: lane q
// covers classes q, q+4, ... (coalesced 16B segments, 4x fewer loads than
// 1-thread-per-box). Cross-lane combine preserves np.argmax first-max.
// ---------------------------------------------------------------------------
__global__ void __launch_bounds__(256)
nms_score_kernel(const float* __restrict__ x,
                 float* __restrict__ scores,
                 int* __restrict__ cls_id,
                 unsigned* __restrict__ hist) {
    int b = blockIdx.y;
    int g = threadIdx.x >> 2;          // box group 0..63
    int q = threadIdx.x & 3;
    int i = blockIdx.x * 64 + g;
    if (i >= N) return;                // whole 4-lane group exits together
    const float* p = x + ((size_t)b * N + i) * ROW;
    float obj = p[4];
    float best = -1e30f;
    int bc = 127;
    if (obj > 0.3f) {
        #pragma unroll
        for (int k = 0; k < 20; ++k) {
            int c = q + 4 * k;
            float v = __fmul_rn(p[5 + c], obj);   // exact, no FMA
            if (v > best) { best = v; bc = c; }   // strict >: first-max in-lane
        }
    }
    // combine across the 4 lanes: higher v wins; tie -> smaller class index
    #pragma unroll
    for (int m = 1; m < 4; m <<= 1) {
        float ov = __shfl_xor(best, m, 64);
        int   oc = __shfl_xor(bc, m, 64);
        if (ov > best || (ov == best && oc < bc)) { best = ov; bc = oc; }
    }
    if (q == 0) {
        float score = -1.0f;
        int cid = (bc == 127) ? 0 : bc;
        if (obj > 0.3f && best > 0.3f) {
            score = best;
            int qq = (int)(__fmul_rn(best, 16384.0f));
            if (qq > NBUCKET - 1) qq = NBUCKET - 1;
            atomicAdd(&hist[b * NBUCKET + qq], 1u);
        }
        scores[b * N + i] = score;
        cls_id[b * N + i] = cid;
    }
}

// ---------------------------------------------------------------------------
// Kernel 3 (fused select): counting sort by histogram rank. Unchanged from R4.
// ---------------------------------------------------------------------------
__global__ void __launch_bounds__(1024, 1)
nms_select_kernel(const unsigned* __restrict__ hist,
                  const float* __restrict__ scores,
                  const float* __restrict__ x,
                  const int* __restrict__ cls_id,
                  float* __restrict__ top_s,
                  float* __restrict__ boxes,
                  int* __restrict__ clsk,
                  float* __restrict__ shifted,
                  float* __restrict__ area) {
    __shared__ unsigned loff[NBUCKET];          // 64 KB: hist -> start ranks
    __shared__ unsigned lcnt16[NBUCKET / 2];    // 32 KB: packed u16 cursors
    __shared__ unsigned long long lk[CAND_CAP]; // 32 KB: packed sort keys
    __shared__ unsigned wsum[16];

    int b = blockIdx.x;
    int t = threadIdx.x;
    int ln = t & 63, wv = t >> 6;

    {
        const uint4* src = (const uint4*)(hist + b * NBUCKET);
        uint4* dst = (uint4*)loff;
        for (int k = t; k < NBUCKET / 4; k += 1024) dst[k] = src[k];
    }
    for (int k = t; k < NBUCKET / 2; k += 1024) lcnt16[k] = 0u;
    for (int k = t; k < CAND_CAP; k += 1024) lk[k] = 0ULL;
    __syncthreads();

    // descending exclusive scan: loff[q] = sum of hist[q'] for q' > q
    unsigned v[16];
    unsigned S = 0;
    int base_j = t * 16;
    #pragma unroll
    for (int k = 0; k < 16; ++k) { v[k] = loff[NBUCKET - 1 - (base_j + k)]; S += v[k]; }
    unsigned pref = S;
    #pragma unroll
    for (int o = 1; o < 64; o <<= 1) { unsigned u = __shfl_up(pref, o, 64); if (ln >= o) pref += u; }
    if (ln == 63) wsum[wv] = pref;
    __syncthreads();
    unsigned wbase = 0;
    for (int w = 0; w < wv; ++w) wbase += wsum[w];
    unsigned running = wbase + pref - S;
    #pragma unroll
    for (int k = 0; k < 16; ++k) {
        loff[NBUCKET - 1 - (base_j + k)] = running;
        running += v[k];
    }
    __syncthreads();

    // placement (counting sort)
    for (int i = t; i < N; i += 1024) {
        float s = scores[b * N + i];
        if (s > 0.0f) {
            int q = (int)(__fmul_rn(s, 16384.0f));
            if (q > NBUCKET - 1) q = NBUCKET - 1;
            unsigned start = loff[q];
            if (start < CAND_CAP) {
                unsigned sh = (q & 1) * 16;
                unsigned old = atomicAdd(&lcnt16[q >> 1], 1u << sh);
                unsigned rank = (old >> sh) & 0xFFFFu;
                unsigned pos = start + rank;
                if (pos < CAND_CAP) {
                    unsigned long long key =
                        ((unsigned long long)__float_as_uint(s) << 32) | (unsigned)(~i);
                    lk[pos] = key;
                }
            }
        }
    }
    __syncthreads();

    // per-bucket insertion sort (descending keys), disjoint ranges
    for (int q = t; q < NBUCKET; q += 1024) {
        unsigned start = loff[q];
        if (start < CAND_CAP) {
            unsigned c = (lcnt16[q >> 1] >> ((q & 1) * 16)) & 0xFFFFu;
            unsigned m = c;
            if (m > CAND_CAP - start) m = CAND_CAP - start;
            if (m >= 2) {
                for (unsigned a = start + 1; a < start + m; ++a) {
                    unsigned long long kv = lk[a];
                    unsigned p2 = a;
                    while (p2 > start && lk[p2 - 1] < kv) { lk[p2] = lk[p2 - 1]; --p2; }
                    lk[p2] = kv;
                }
            }
        }
    }
    __syncthreads();

    // gather top-K
    for (int r = t; r < K; r += 1024) {
        unsigned long long key = lk[r];
        float s;
        int idx;
        float x1, y1, x2, y2;
        int c;
        if (key == 0ULL) {
            s = -1.0f; x1 = y1 = x2 = y2 = 0.0f; c = 0;
        } else {
            s = __uint_as_float((unsigned)(key >> 32));
            idx = (int)(~(unsigned)key);
            const float* p = x + ((size_t)b * N + idx) * ROW;
            float cx = p[0], cy = p[1], w = p[2], h = p[3];
            float hx = __fmul_rn(w, 0.5f);
            float hy = __fmul_rn(h, 0.5f);
            x1 = __fsub_rn(cx, hx); y1 = __fsub_rn(cy, hy);
            x2 = __fadd_rn(cx, hx); y2 = __fadd_rn(cy, hy);
            c = cls_id[b * N + idx];
        }
        int o = b * K + r;
        top_s[o] = s;
        boxes[o * 4 + 0] = x1; boxes[o * 4 + 1] = y1;
        boxes[o * 4 + 2] = x2; boxes[o * 4 + 3] = y2;
        clsk[o] = c;
        float sh = __fmul_rn((float)c, 4096.0f);
        float sx1 = __fadd_rn(x1, sh), sy1 = __fadd_rn(y1, sh);
        float sx2 = __fadd_rn(x2, sh), sy2 = __fadd_rn(y2, sh);
        shifted[o * 4 + 0] = sx1; shifted[o * 4 + 1] = sy1;
        shifted[o * 4 + 2] = sx2; shifted[o * 4 + 3] = sy2;
        area[o] = __fmul_rn(__fsub_rn(sx2, sx1), __fsub_rn(sy2, sy1));
    }
}

// ---------------------------------------------------------------------------
// Kernel 4: transposed IoU bitmask. Block (jb, ib<=jb): for each j in chunk jb,
// ballot over i-lanes of chunk ib -> maskT[b][j][ib] = suppressors of j there.
// Lower-triangle blocks return without writing (those words are never read).
// ---------------------------------------------------------------------------
__global__ void nms_mask_kernel(const float* __restrict__ shifted,
                                const float* __restrict__ area,
                                unsigned long long* __restrict__ maskT) {
    int jb = blockIdx.x, ib = blockIdx.y, b = blockIdx.z;
    if (ib > jb) return;
    int t = threadIdx.x;   // 0..63
    int i = ib * 64 + t;

    __shared__ float jbox[64][4];
    __shared__ float jarea[64];
    int j0 = jb * 64;
    {
        const float* sb = shifted + ((size_t)b * K + j0 + t) * 4;
        jbox[t][0] = sb[0]; jbox[t][1] = sb[1]; jbox[t][2] = sb[2]; jbox[t][3] = sb[3];
        jarea[t] = area[b * K + j0 + t];
    }
    __syncthreads();

    const float* ab = shifted + ((size_t)b * K + i) * 4;
    float ax1 = ab[0], ay1 = ab[1], ax2 = ab[2], ay2 = ab[3];
    float aarea = area[b * K + i];

    unsigned long long mycol = 0ULL;
    for (int jl = 0; jl < 64; ++jl) {
        int j = j0 + jl;
        bool cond = false;
        if (j > i) {
            float lx = fmaxf(ax1, jbox[jl][0]);
            float ly = fmaxf(ay1, jbox[jl][1]);
            float rx = fminf(ax2, jbox[jl][2]);
            float ry = fminf(ay2, jbox[jl][3]);
            float w = fmaxf(__fsub_rn(rx, lx), 0.0f);
            float h = fmaxf(__fsub_rn(ry, ly), 0.0f);
            float inter = __fmul_rn(w, h);
            float denom = __fadd_rn(__fsub_rn(__fadd_rn(aarea, jarea[jl]), inter), 1e-9f);
            float iou = __fdiv_rn(inter, denom);
            cond = iou > 0.6f;
        }
        unsigned long long colm = __ballot(cond);   // bits over i for column jl
        if (t == jl) mycol = colm;
    }
    maskT[((size_t)b * K + j0 + t) * NCHUNK + ib] = mycol;
}

// ---------------------------------------------------------------------------
// Kernel 5: parallel fixpoint greedy reduce. kept(j) = valid(j) and no kept
// suppressor. Round 1 decides all boxes with empty suppressor rows (~99%);
// remaining chains resolve in a few snapshot rounds. 1024 thr/batch, 2 boxes
// per thread, kept/decided bitmaps in LDS.
// ---------------------------------------------------------------------------
__global__ void __launch_bounds__(1024)
nms_reduce_kernel(const unsigned long long* __restrict__ maskT,
                  const float* __restrict__ top_s,
                  unsigned long long* __restrict__ keepw) {
    int b = blockIdx.x;
    int t = threadIdx.x;
    int ln = t & 63, wv = t >> 6;   // 16 waves
    __shared__ unsigned long long kept[NCHUNK], decided[NCHUNK];
    __shared__ unsigned long long snapk[NCHUNK], snapd[NCHUNK];
    __shared__ int nundec;
    if (t == 0) nundec = 0;
    __syncthreads();

    int st[2];   // 1 = decided
    #pragma unroll
    for (int h = 0; h < 2; ++h) {
        int j = t + h * 1024;
        bool valid = top_s[b * K + j] > 0.0f;
        const unsigned long long* row = maskT + ((size_t)b * K + j) * NCHUNK;
        int nw = (j >> 6) + 1;
        unsigned long long orall = 0ULL;
        for (int w = 0; w < nw; ++w) orall |= row[w];
        bool k_local = false, d_local;
        if (!valid)             { d_local = true; }
        else if (orall == 0ULL) { k_local = true; d_local = true; }
        else                    { d_local = false; }
        st[h] = d_local ? 1 : 0;
        unsigned long long kb = __ballot(k_local);
        unsigned long long db = __ballot(d_local);
        if (ln == 0) {
            int word = wv + h * 16;
            kept[word] = kb;
            decided[word] = db;
            if (~db != 0ULL) atomicAdd(&nundec, __popcll(~db));
        }
    }

    for (int round = 0; round < 2048; ++round) {
        __syncthreads();
        if (nundec == 0) break;
        if (t < NCHUNK) { snapd[t] = decided[t]; snapk[t] = kept[t]; }
        __syncthreads();
        #pragma unroll
        for (int h = 0; h < 2; ++h) {
            if (st[h]) continue;
            int j = t + h * 1024;
            const unsigned long long* row = maskT + ((size_t)b * K + j) * NCHUNK;
            int nw = (j >> 6) + 1;
            unsigned long long pend = 0ULL, sup = 0ULL;
            for (int w = 0; w < nw; ++w) {
                unsigned long long r = row[w];
                pend |= r & ~snapd[w];
                sup  |= r & snapk[w];
            }
            if (pend == 0ULL) {   // all suppressors finalized
                unsigned long long bit = 1ULL << (j & 63);
                if (sup == 0ULL) atomicOr(&kept[j >> 6], bit);
                atomicOr(&decided[j >> 6], bit);
                st[h] = 1;
                atomicSub(&nundec, 1);
            }
        }
    }
    __syncthreads();
    if (t < NCHUNK) keepw[b * NCHUNK + t] = kept[t];
}

// ---------------------------------------------------------------------------
// Kernel 6: final top-300 + output write. One wave per batch.
// ---------------------------------------------------------------------------
__global__ void nms_out_kernel(const unsigned long long* __restrict__ keepw,
                               const float* __restrict__ top_s,
                               const float* __restrict__ boxes,
                               const int* __restrict__ clsk,
                               float* __restrict__ out) {
    int b = blockIdx.x;
    int lane = threadIdx.x;   // 0..63
    int total = 0;
    for (int c = 0; c < K / 64; ++c) {
        bool k = ((keepw[b * NCHUNK + c] >> lane) & 1ULL) != 0ULL;
        unsigned long long m = __ballot(k);
        total += __popcll(m);
    }
    float* dets  = out + (size_t)b * MAXDET * 6;
    float* flags = out + (size_t)B * MAXDET * 6 + (size_t)b * MAXDET;
    unsigned long long below = (lane == 0) ? 0ULL : (~0ULL >> (64 - lane));
    int kc = 0, nc = 0;
    for (int c = 0; c < K / 64; ++c) {
        int i = c * 64 + lane;
        bool k = ((keepw[b * NCHUNK + c] >> lane) & 1ULL) != 0ULL;
        unsigned long long m = __ballot(k);
        int pc = __popcll(m);
        int slot = k ? (kc + __popcll(m & below))
                     : (total + nc + __popcll((~m) & below));
        if (slot < MAXDET) {
            int o = b * K + i;
            dets[slot * 6 + 0] = boxes[o * 4 + 0];
            dets[slot * 6 + 1] = boxes[o * 4 + 1];
            dets[slot * 6 + 2] = boxes[o * 4 + 2];
            dets[slot * 6 + 3] = boxes[o * 4 + 3];
            dets[slot * 6 + 4] = top_s[o];
            dets[slot * 6 + 5] = (float)clsk[o];
            flags[slot] = k ? 1.0f : 0.0f;
        }
        kc += pc;
        nc += 64 - pc;
    }
}

// ---------------------------------------------------------------------------
extern "C" void kernel_launch(void* const* d_in, const int* in_sizes, int n_in,
                              void* d_out, int out_size, void* d_ws, size_t ws_size,
                              hipStream_t stream) {
    const float* x = (const float*)d_in[0];
    float* out = (float*)d_out;

    char* ws = (char*)d_ws;
    size_t off = 0;
    auto alloc = [&](size_t bytes) -> void* {
        void* p = ws + off;
        off += bytes;
        off = (off + 255) & ~(size_t)255;
        return p;
    };

    float*    scores = (float*)    alloc((size_t)B * N * 4);
    int*      cls_id = (int*)      alloc((size_t)B * N * 4);
    unsigned* hist   = (unsigned*) alloc((size_t)B * NBUCKET * 4);
    float*    top_s  = (float*)    alloc((size_t)B * K * 4);
    float*    boxes  = (float*)    alloc((size_t)B * K * 4 * 4);
    int*      clsk   = (int*)      alloc((size_t)B * K * 4);
    float*    shifted= (float*)    alloc((size_t)B * K * 4 * 4);
    float*    area   = (float*)    alloc((size_t)B * K * 4);
    unsigned long long* maskT = (unsigned long long*) alloc((size_t)B * K * NCHUNK * 8);
    unsigned long long* keepw = (unsigned long long*) alloc((size_t)B * NCHUNK * 8);
    (void)ws_size; // needs ~7.4 MB

    nms_zero_kernel<<<(B * NBUCKET + 255) / 256, 256, 0, stream>>>(hist);
    nms_score_kernel<<<dim3((N + 63) / 64, B), 256, 0, stream>>>(x, scores, cls_id, hist);
    nms_select_kernel<<<B, 1024, 0, stream>>>(hist, scores, x, cls_id,
                                              top_s, boxes, clsk, shifted, area);
    nms_mask_kernel<<<dim3(NCHUNK, NCHUNK, B), 64, 0, stream>>>(shifted, area, maskT);
    nms_reduce_kernel<<<B, 1024, 0, stream>>>(maskT, top_s, keepw);
    nms_out_kernel<<<B, 64, 0, stream>>>(keepw, top_s, boxes, clsk, out);
}

// Round 6
// 179.042 us; speedup vs baseline: 6.6254x; 1.0373x over previous
//
#include <hip/hip_runtime.h>
#include <hip/hip_bf16.h>

#define B 8
#define N 25200
#define ROW 85
#define NC 80
#define K 2048
#define MAXDET 300
#define NBUCKET 16384
#define CAND_CAP 4096
#define NCHUNK 32   /* K/64 */
#define STILE 64    /* score tile rows */

// ---------------------------------------------------------------------------
// Kernel 1: score/cls per box. Tile of 64 rows staged to LDS via coalesced
// float4 loads (rows are 85 floats; 64*85 floats = 1360 float4, 16B-aligned
// because (b*N + i0)*85*4 is divisible by 16 for i0 % 64 == 0).
// 4 lanes per box, exact np.argmax first-max tie-break via shuffle combine.
// ---------------------------------------------------------------------------
__global__ void __launch_bounds__(256)
nms_score_kernel(const float* __restrict__ x,
                 float* __restrict__ scores,
                 int* __restrict__ cls_id) {
    int b = blockIdx.y;
    int i0 = blockIdx.x * STILE;
    int rows = N - i0; if (rows > STILE) rows = STILE;
    __shared__ float lx[STILE * ROW];   // 21760 B
    {
        const float4* s4 = (const float4*)(x + ((size_t)b * N + i0) * ROW);
        float4* d4 = (float4*)lx;
        int nv = rows * ROW / 4;        // 1360 or 1020 (both exact)
        for (int k = threadIdx.x; k < nv; k += 256) d4[k] = s4[k];
    }
    __syncthreads();
    int g = threadIdx.x >> 2;          // box in tile
    int q = threadIdx.x & 3;
    if (g >= rows) return;             // uniform across the 4-lane group
    const float* p = lx + g * ROW;
    float obj = p[4];
    float best = -1e30f;
    int bc = 127;
    if (obj > 0.3f) {
        #pragma unroll
        for (int k = 0; k < 20; ++k) {
            int c = q + 4 * k;
            float v = __fmul_rn(p[5 + c], obj);   // exact, no FMA
            if (v > best) { best = v; bc = c; }   // strict >: in-lane first-max
        }
    }
    #pragma unroll
    for (int m = 1; m < 4; m <<= 1) {   // combine: higher v, tie -> smaller class
        float ov = __shfl_xor(best, m, 64);
        int   oc = __shfl_xor(bc, m, 64);
        if (ov > best || (ov == best && oc < bc)) { best = ov; bc = oc; }
    }
    if (q == 0) {
        int i = i0 + g;
        float score = (obj > 0.3f && best > 0.3f) ? best : -1.0f;
        scores[b * N + i] = score;
        cls_id[b * N + i] = (bc == 127) ? 0 : bc;
    }
}

// ---------------------------------------------------------------------------
// Kernel 2 (fused select): LDS histogram of quantized scores -> descending
// exclusive scan -> counting-sort placement with packed-u16 cursors ->
// per-bucket insertion sort -> gather top-K boxes/cls/shifted/area.
// LDS: 64KB loff + 32KB cursors + 32KB keys = 128KB -> 1 block/CU.
// ---------------------------------------------------------------------------
__global__ void __launch_bounds__(1024, 1)
nms_select_kernel(const float* __restrict__ scores,
                  const float* __restrict__ x,
                  const int* __restrict__ cls_id,
                  float* __restrict__ top_s,
                  float* __restrict__ boxes,
                  int* __restrict__ clsk,
                  float* __restrict__ shifted,
                  float* __restrict__ area) {
    __shared__ unsigned loff[NBUCKET];          // histogram, then start ranks
    __shared__ unsigned lcnt16[NBUCKET / 2];    // packed u16 cursors
    __shared__ unsigned long long lk[CAND_CAP]; // packed sort keys
    __shared__ unsigned wsum[16];

    int b = blockIdx.x;
    int t = threadIdx.x;
    int ln = t & 63, wv = t >> 6;

    {   // zero histogram + cursors + keys
        uint4 z = {0u, 0u, 0u, 0u};
        uint4* d1 = (uint4*)loff;
        for (int k = t; k < NBUCKET / 4; k += 1024) d1[k] = z;
        uint4* d2 = (uint4*)lcnt16;
        for (int k = t; k < NBUCKET / 8; k += 1024) d2[k] = z;
    }
    for (int k = t; k < CAND_CAP; k += 1024) lk[k] = 0ULL;
    __syncthreads();

    // build histogram from scores
    for (int i = t; i < N; i += 1024) {
        float s = scores[b * N + i];
        if (s > 0.0f) {
            int q = (int)(__fmul_rn(s, 16384.0f));
            if (q > NBUCKET - 1) q = NBUCKET - 1;
            atomicAdd(&loff[q], 1u);
        }
    }
    __syncthreads();

    // descending exclusive scan: loff[q] = count of elements in buckets > q
    unsigned v[16];
    unsigned S = 0;
    int base_j = t * 16;
    #pragma unroll
    for (int k = 0; k < 16; ++k) { v[k] = loff[NBUCKET - 1 - (base_j + k)]; S += v[k]; }
    unsigned pref = S;
    #pragma unroll
    for (int o = 1; o < 64; o <<= 1) { unsigned u = __shfl_up(pref, o, 64); if (ln >= o) pref += u; }
    if (ln == 63) wsum[wv] = pref;
    __syncthreads();
    unsigned wbase = 0;
    for (int w = 0; w < wv; ++w) wbase += wsum[w];
    unsigned running = wbase + pref - S;
    #pragma unroll
    for (int k = 0; k < 16; ++k) {
        loff[NBUCKET - 1 - (base_j + k)] = running;
        running += v[k];
    }
    __syncthreads();

    // placement (counting sort)
    for (int i = t; i < N; i += 1024) {
        float s = scores[b * N + i];
        if (s > 0.0f) {
            int q = (int)(__fmul_rn(s, 16384.0f));
            if (q > NBUCKET - 1) q = NBUCKET - 1;
            unsigned start = loff[q];
            if (start < CAND_CAP) {
                unsigned sh = (q & 1) * 16;
                unsigned old = atomicAdd(&lcnt16[q >> 1], 1u << sh);
                unsigned rank = (old >> sh) & 0xFFFFu;
                unsigned pos = start + rank;
                if (pos < CAND_CAP) {
                    unsigned long long key =
                        ((unsigned long long)__float_as_uint(s) << 32) | (unsigned)(~i);
                    lk[pos] = key;
                }
            }
        }
    }
    __syncthreads();

    // per-bucket insertion sort (descending keys), disjoint ranges
    for (int q = t; q < NBUCKET; q += 1024) {
        unsigned start = loff[q];
        if (start < CAND_CAP) {
            unsigned c = (lcnt16[q >> 1] >> ((q & 1) * 16)) & 0xFFFFu;
            unsigned m = c;
            if (m > CAND_CAP - start) m = CAND_CAP - start;
            if (m >= 2) {
                for (unsigned a = start + 1; a < start + m; ++a) {
                    unsigned long long kv = lk[a];
                    unsigned p2 = a;
                    while (p2 > start && lk[p2 - 1] < kv) { lk[p2] = lk[p2 - 1]; --p2; }
                    lk[p2] = kv;
                }
            }
        }
    }
    __syncthreads();

    // gather top-K
    for (int r = t; r < K; r += 1024) {
        unsigned long long key = lk[r];
        float s;
        int idx;
        float x1, y1, x2, y2;
        int c;
        if (key == 0ULL) {
            s = -1.0f; x1 = y1 = x2 = y2 = 0.0f; c = 0;
        } else {
            s = __uint_as_float((unsigned)(key >> 32));
            idx = (int)(~(unsigned)key);
            const float* p = x + ((size_t)b * N + idx) * ROW;
            float cx = p[0], cy = p[1], w = p[2], h = p[3];
            float hx = __fmul_rn(w, 0.5f);
            float hy = __fmul_rn(h, 0.5f);
            x1 = __fsub_rn(cx, hx); y1 = __fsub_rn(cy, hy);
            x2 = __fadd_rn(cx, hx); y2 = __fadd_rn(cy, hy);
            c = cls_id[b * N + idx];
        }
        int o = b * K + r;
        top_s[o] = s;
        boxes[o * 4 + 0] = x1; boxes[o * 4 + 1] = y1;
        boxes[o * 4 + 2] = x2; boxes[o * 4 + 3] = y2;
        clsk[o] = c;
        float sh = __fmul_rn((float)c, 4096.0f);
        float sx1 = __fadd_rn(x1, sh), sy1 = __fadd_rn(y1, sh);
        float sx2 = __fadd_rn(x2, sh), sy2 = __fadd_rn(y2, sh);
        shifted[o * 4 + 0] = sx1; shifted[o * 4 + 1] = sy1;
        shifted[o * 4 + 2] = sx2; shifted[o * 4 + 3] = sy2;
        area[o] = __fmul_rn(__fsub_rn(sx2, sx1), __fsub_rn(sy2, sy1));
    }
}

// ---------------------------------------------------------------------------
// Kernel 3: transposed IoU bitmask, triangular grid packing (528 blocks/batch,
// no early-return blocks). Block L -> (jb, ib<=jb); for each j in chunk jb,
// ballot over i-lanes of chunk ib -> maskT[b][j][ib] = suppressors of j.
// ---------------------------------------------------------------------------
__global__ void nms_mask_kernel(const float* __restrict__ shifted,
                                const float* __restrict__ area,
                                unsigned long long* __restrict__ maskT) {
    int L = blockIdx.x, b = blockIdx.y;
    int jb = (int)((__fsqrt_rn(8.0f * (float)L + 1.0f) - 1.0f) * 0.5f);
    while ((jb + 1) * (jb + 2) / 2 <= L) ++jb;   // fixup fp error
    while (jb * (jb + 1) / 2 > L) --jb;
    int ib = L - jb * (jb + 1) / 2;
    int t = threadIdx.x;   // 0..63
    int i = ib * 64 + t;

    __shared__ float jbox[64][4];
    __shared__ float jarea[64];
    int j0 = jb * 64;
    {
        const float* sb = shifted + ((size_t)b * K + j0 + t) * 4;
        jbox[t][0] = sb[0]; jbox[t][1] = sb[1]; jbox[t][2] = sb[2]; jbox[t][3] = sb[3];
        jarea[t] = area[b * K + j0 + t];
    }
    __syncthreads();

    const float* ab = shifted + ((size_t)b * K + i) * 4;
    float ax1 = ab[0], ay1 = ab[1], ax2 = ab[2], ay2 = ab[3];
    float aarea = area[b * K + i];

    unsigned long long mycol = 0ULL;
    for (int jl = 0; jl < 64; ++jl) {
        int j = j0 + jl;
        bool cond = false;
        if (j > i) {
            float lx = fmaxf(ax1, jbox[jl][0]);
            float ly = fmaxf(ay1, jbox[jl][1]);
            float rx = fminf(ax2, jbox[jl][2]);
            float ry = fminf(ay2, jbox[jl][3]);
            float w = fmaxf(__fsub_rn(rx, lx), 0.0f);
            float h = fmaxf(__fsub_rn(ry, ly), 0.0f);
            float inter = __fmul_rn(w, h);
            float denom = __fadd_rn(__fsub_rn(__fadd_rn(aarea, jarea[jl]), inter), 1e-9f);
            float iou = __fdiv_rn(inter, denom);   // exact ref order + division
            cond = iou > 0.6f;
        }
        unsigned long long colm = __ballot(cond);
        if (t == jl) mycol = colm;
    }
    maskT[((size_t)b * K + j0 + t) * NCHUNK + ib] = mycol;
}

// ---------------------------------------------------------------------------
// Kernel 4: parallel fixpoint greedy reduce + fused top-300 output.
// ---------------------------------------------------------------------------
__global__ void __launch_bounds__(1024)
nms_reduce_out_kernel(const unsigned long long* __restrict__ maskT,
                      const float* __restrict__ top_s,
                      const float* __restrict__ boxes,
                      const int* __restrict__ clsk,
                      float* __restrict__ out) {
    int b = blockIdx.x;
    int t = threadIdx.x;
    int ln = t & 63, wv = t >> 6;   // 16 waves
    __shared__ unsigned long long kept[NCHUNK], decided[NCHUNK];
    __shared__ unsigned long long snapk[NCHUNK], snapd[NCHUNK];
    __shared__ int nundec;
    if (t == 0) nundec = 0;
    __syncthreads();

    int st[2];   // 1 = decided
    #pragma unroll
    for (int h = 0; h < 2; ++h) {
        int j = t + h * 1024;
        bool valid = top_s[b * K + j] > 0.0f;
        const unsigned long long* row = maskT + ((size_t)b * K + j) * NCHUNK;
        int nw = (j >> 6) + 1;
        unsigned long long orall = 0ULL;
        for (int w = 0; w < nw; ++w) orall |= row[w];
        bool k_local = false, d_local;
        if (!valid)             { d_local = true; }
        else if (orall == 0ULL) { k_local = true; d_local = true; }
        else                    { d_local = false; }
        st[h] = d_local ? 1 : 0;
        unsigned long long kb = __ballot(k_local);
        unsigned long long db = __ballot(d_local);
        if (ln == 0) {
            int word = wv + h * 16;
            kept[word] = kb;
            decided[word] = db;
            if (~db != 0ULL) atomicAdd(&nundec, __popcll(~db));
        }
    }

    for (int round = 0; round < 2048; ++round) {
        __syncthreads();
        if (nundec == 0) break;
        if (t < NCHUNK) { snapd[t] = decided[t]; snapk[t] = kept[t]; }
        __syncthreads();
        #pragma unroll
        for (int h = 0; h < 2; ++h) {
            if (st[h]) continue;
            int j = t + h * 1024;
            const unsigned long long* row = maskT + ((size_t)b * K + j) * NCHUNK;
            int nw = (j >> 6) + 1;
            unsigned long long pend = 0ULL, sup = 0ULL;
            for (int w = 0; w < nw; ++w) {
                unsigned long long r = row[w];
                pend |= r & ~snapd[w];
                sup  |= r & snapk[w];
            }
            if (pend == 0ULL) {
                unsigned long long bit = 1ULL << (j & 63);
                if (sup == 0ULL) atomicOr(&kept[j >> 6], bit);
                atomicOr(&decided[j >> 6], bit);
                st[h] = 1;
                atomicSub(&nundec, 1);
            }
        }
    }
    __syncthreads();

    // fused output phase: wave 0 only (kept[] lives in LDS)
    if (wv == 0) {
        int lane = ln;
        int total = 0;
        for (int c = 0; c < NCHUNK; ++c) {
            bool k = ((kept[c] >> lane) & 1ULL) != 0ULL;
            unsigned long long m = __ballot(k);
            total += __popcll(m);
        }
        float* dets  = out + (size_t)b * MAXDET * 6;
        float* flags = out + (size_t)B * MAXDET * 6 + (size_t)b * MAXDET;
        unsigned long long below = (lane == 0) ? 0ULL : (~0ULL >> (64 - lane));
        int kc = 0, nc = 0;
        for (int c = 0; c < NCHUNK; ++c) {
            int i = c * 64 + lane;
            bool k = ((kept[c] >> lane) & 1ULL) != 0ULL;
            unsigned long long m = __ballot(k);
            int pc = __popcll(m);
            int slot = k ? (kc + __popcll(m & below))
                         : (total + nc + __popcll((~m) & below));
            if (slot < MAXDET) {
                int o = b * K + i;
                dets[slot * 6 + 0] = boxes[o * 4 + 0];
                dets[slot * 6 + 1] = boxes[o * 4 + 1];
                dets[slot * 6 + 2] = boxes[o * 4 + 2];
                dets[slot * 6 + 3] = boxes[o * 4 + 3];
                dets[slot * 6 + 4] = top_s[o];
                dets[slot * 6 + 5] = (float)clsk[o];
                flags[slot] = k ? 1.0f : 0.0f;
            }
            kc += pc;
            nc += 64 - pc;
        }
    }
}

// ---------------------------------------------------------------------------
extern "C" void kernel_launch(void* const* d_in, const int* in_sizes, int n_in,
                              void* d_out, int out_size, void* d_ws, size_t ws_size,
                              hipStream_t stream) {
    const float* x = (const float*)d_in[0];
    float* out = (float*)d_out;

    char* ws = (char*)d_ws;
    size_t off = 0;
    auto alloc = [&](size_t bytes) -> void* {
        void* p = ws + off;
        off += bytes;
        off = (off + 255) & ~(size_t)255;
        return p;
    };

    float*    scores = (float*)    alloc((size_t)B * N * 4);
    int*      cls_id = (int*)      alloc((size_t)B * N * 4);
    float*    top_s  = (float*)    alloc((size_t)B * K * 4);
    float*    boxes  = (float*)    alloc((size_t)B * K * 4 * 4);
    int*      clsk   = (int*)      alloc((size_t)B * K * 4);
    float*    shifted= (float*)    alloc((size_t)B * K * 4 * 4);
    float*    area   = (float*)    alloc((size_t)B * K * 4);
    unsigned long long* maskT = (unsigned long long*) alloc((size_t)B * K * NCHUNK * 8);
    (void)ws_size; // needs ~6.4 MB

    nms_score_kernel<<<dim3((N + STILE - 1) / STILE, B), 256, 0, stream>>>(x, scores, cls_id);
    nms_select_kernel<<<B, 1024, 0, stream>>>(scores, x, cls_id,
                                              top_s, boxes, clsk, shifted, area);
    nms_mask_kernel<<<dim3(NCHUNK * (NCHUNK + 1) / 2, B), 64, 0, stream>>>(shifted, area, maskT);
    nms_reduce_out_kernel<<<B, 1024, 0, stream>>>(maskT, top_s, boxes, clsk, out);
}

// Round 7
// 160.990 us; speedup vs baseline: 7.3683x; 1.1121x over previous
//
#include <hip/hip_runtime.h>
#include <hip/hip_bf16.h>

#define B 8
#define N 25200
#define ROW 85
#define NC 80
#define K 2048
#define MAXDET 300
#define NBUCKET 16384
#define CAND_CAP 4096
#define NCHUNK 32   /* K/64 */
#define STILE 64    /* score tile rows */

// ---------------------------------------------------------------------------
// Kernel 1: score/cls per box. 64-row tile staged to LDS via coalesced float4
// loads; 4 lanes per box; exact np.argmax first-max tie-break via shuffles.
// ---------------------------------------------------------------------------
__global__ void __launch_bounds__(256)
nms_score_kernel(const float* __restrict__ x,
                 float* __restrict__ scores,
                 int* __restrict__ cls_id) {
    int b = blockIdx.y;
    int i0 = blockIdx.x * STILE;
    int rows = N - i0; if (rows > STILE) rows = STILE;
    __shared__ float lx[STILE * ROW];   // 21760 B
    {
        const float4* s4 = (const float4*)(x + ((size_t)b * N + i0) * ROW);
        float4* d4 = (float4*)lx;
        int nv = rows * ROW / 4;        // 1360 or 1020 (both exact)
        for (int k = threadIdx.x; k < nv; k += 256) d4[k] = s4[k];
    }
    __syncthreads();
    int g = threadIdx.x >> 2;          // box in tile
    int q = threadIdx.x & 3;
    if (g >= rows) return;             // uniform across the 4-lane group
    const float* p = lx + g * ROW;
    float obj = p[4];
    float best = -1e30f;
    int bc = 127;
    if (obj > 0.3f) {
        #pragma unroll
        for (int k = 0; k < 20; ++k) {
            int c = q + 4 * k;
            float v = __fmul_rn(p[5 + c], obj);   // exact, no FMA
            if (v > best) { best = v; bc = c; }   // strict >: in-lane first-max
        }
    }
    #pragma unroll
    for (int m = 1; m < 4; m <<= 1) {   // combine: higher v, tie -> smaller class
        float ov = __shfl_xor(best, m, 64);
        int   oc = __shfl_xor(bc, m, 64);
        if (ov > best || (ov == best && oc < bc)) { best = ov; bc = oc; }
    }
    if (q == 0) {
        int i = i0 + g;
        float score = (obj > 0.3f && best > 0.3f) ? best : -1.0f;
        scores[b * N + i] = score;
        cls_id[b * N + i] = (bc == 127) ? 0 : bc;
    }
}

// ---------------------------------------------------------------------------
// Kernel 2 (fused select): LDS histogram (scores register-cached, single
// global pass) -> descending exclusive scan (uint4-vectorized LDS) ->
// counting-sort placement from registers -> per-bucket insertion sort ->
// gather top-K boxes/cls/shifted/area. 128 KB LDS -> 1 block/CU.
// ---------------------------------------------------------------------------
__global__ void __launch_bounds__(1024, 1)
nms_select_kernel(const float* __restrict__ scores,
                  const float* __restrict__ x,
                  const int* __restrict__ cls_id,
                  float* __restrict__ top_s,
                  float* __restrict__ boxes,
                  int* __restrict__ clsk,
                  float* __restrict__ shifted,
                  float* __restrict__ area) {
    __shared__ unsigned loff[NBUCKET];          // histogram, then start ranks
    __shared__ unsigned lcnt16[NBUCKET / 2];    // packed u16 cursors
    __shared__ unsigned long long lk[CAND_CAP]; // packed sort keys
    __shared__ unsigned wsum[16];

    int b = blockIdx.x;
    int t = threadIdx.x;
    int ln = t & 63, wv = t >> 6;
    constexpr int NITER = (N + 1023) / 1024;    // 25

    {   // zero histogram + cursors + keys
        uint4 z = {0u, 0u, 0u, 0u};
        uint4* d1 = (uint4*)loff;
        for (int k = t; k < NBUCKET / 4; k += 1024) d1[k] = z;
        uint4* d2 = (uint4*)lcnt16;
        for (int k = t; k < NBUCKET / 8; k += 1024) d2[k] = z;
    }
    for (int k = t; k < CAND_CAP; k += 1024) lk[k] = 0ULL;
    __syncthreads();

    // histogram pass: single global read, cache scores in registers
    float sreg[NITER];
    #pragma unroll
    for (int r = 0; r < NITER; ++r) {
        int i = t + r * 1024;
        float s = (i < N) ? scores[b * N + i] : -1.0f;
        sreg[r] = s;
        if (s > 0.0f) {
            int q = (int)(__fmul_rn(s, 16384.0f));
            if (q > NBUCKET - 1) q = NBUCKET - 1;
            atomicAdd(&loff[q], 1u);
        }
    }
    __syncthreads();

    // descending exclusive scan: loff[q] = count of elements in buckets > q.
    // thread t owns buckets NBUCKET-1-16t .. NBUCKET-16-16t (k ascending =
    // bucket descending). uint4 loads/stores cut the 32-way-conflict op count.
    unsigned v[16];
    int base_j = t * 16;
    unsigned A4 = (unsigned)(NBUCKET - 16 - base_j) / 4;   // ascending uint4 base
    {
        uint4 u0 = ((uint4*)loff)[A4 + 0];
        uint4 u1 = ((uint4*)loff)[A4 + 1];
        uint4 u2 = ((uint4*)loff)[A4 + 2];
        uint4 u3 = ((uint4*)loff)[A4 + 3];
        unsigned u[16] = {u0.x,u0.y,u0.z,u0.w, u1.x,u1.y,u1.z,u1.w,
                          u2.x,u2.y,u2.z,u2.w, u3.x,u3.y,u3.z,u3.w};
        #pragma unroll
        for (int k = 0; k < 16; ++k) v[k] = u[15 - k];
    }
    unsigned S = 0;
    #pragma unroll
    for (int k = 0; k < 16; ++k) S += v[k];
    unsigned pref = S;
    #pragma unroll
    for (int o = 1; o < 64; o <<= 1) { unsigned u = __shfl_up(pref, o, 64); if (ln >= o) pref += u; }
    if (ln == 63) wsum[wv] = pref;
    __syncthreads();
    unsigned wbase = 0;
    for (int w = 0; w < wv; ++w) wbase += wsum[w];
    unsigned running = wbase + pref - S;
    {
        unsigned o[16];
        #pragma unroll
        for (int k = 0; k < 16; ++k) { o[15 - k] = running; running += v[k]; }
        ((uint4*)loff)[A4 + 0] = make_uint4(o[0],  o[1],  o[2],  o[3]);
        ((uint4*)loff)[A4 + 1] = make_uint4(o[4],  o[5],  o[6],  o[7]);
        ((uint4*)loff)[A4 + 2] = make_uint4(o[8],  o[9],  o[10], o[11]);
        ((uint4*)loff)[A4 + 3] = make_uint4(o[12], o[13], o[14], o[15]);
    }
    __syncthreads();

    // placement (counting sort) from register-cached scores
    #pragma unroll
    for (int r = 0; r < NITER; ++r) {
        float s = sreg[r];
        if (s > 0.0f) {
            int i = t + r * 1024;
            int q = (int)(__fmul_rn(s, 16384.0f));
            if (q > NBUCKET - 1) q = NBUCKET - 1;
            unsigned start = loff[q];
            if (start < CAND_CAP) {
                unsigned sh = (q & 1) * 16;
                unsigned old = atomicAdd(&lcnt16[q >> 1], 1u << sh);
                unsigned rank = (old >> sh) & 0xFFFFu;
                unsigned pos = start + rank;
                if (pos < CAND_CAP) {
                    unsigned long long key =
                        ((unsigned long long)__float_as_uint(s) << 32) | (unsigned)(~i);
                    lk[pos] = key;
                }
            }
        }
    }
    __syncthreads();

    // per-bucket insertion sort (descending keys), disjoint ranges
    for (int q = t; q < NBUCKET; q += 1024) {
        unsigned start = loff[q];
        if (start < CAND_CAP) {
            unsigned c = (lcnt16[q >> 1] >> ((q & 1) * 16)) & 0xFFFFu;
            unsigned m = c;
            if (m > CAND_CAP - start) m = CAND_CAP - start;
            if (m >= 2) {
                for (unsigned a = start + 1; a < start + m; ++a) {
                    unsigned long long kv = lk[a];
                    unsigned p2 = a;
                    while (p2 > start && lk[p2 - 1] < kv) { lk[p2] = lk[p2 - 1]; --p2; }
                    lk[p2] = kv;
                }
            }
        }
    }
    __syncthreads();

    // gather top-K
    for (int r = t; r < K; r += 1024) {
        unsigned long long key = lk[r];
        float s;
        int idx;
        float x1, y1, x2, y2;
        int c;
        if (key == 0ULL) {
            s = -1.0f; x1 = y1 = x2 = y2 = 0.0f; c = 0;
        } else {
            s = __uint_as_float((unsigned)(key >> 32));
            idx = (int)(~(unsigned)key);
            const float* p = x + ((size_t)b * N + idx) * ROW;
            float cx = p[0], cy = p[1], w = p[2], h = p[3];
            float hx = __fmul_rn(w, 0.5f);
            float hy = __fmul_rn(h, 0.5f);
            x1 = __fsub_rn(cx, hx); y1 = __fsub_rn(cy, hy);
            x2 = __fadd_rn(cx, hx); y2 = __fadd_rn(cy, hy);
            c = cls_id[b * N + idx];
        }
        int o = b * K + r;
        top_s[o] = s;
        boxes[o * 4 + 0] = x1; boxes[o * 4 + 1] = y1;
        boxes[o * 4 + 2] = x2; boxes[o * 4 + 3] = y2;
        clsk[o] = c;
        float sh = __fmul_rn((float)c, 4096.0f);
        float sx1 = __fadd_rn(x1, sh), sy1 = __fadd_rn(y1, sh);
        float sx2 = __fadd_rn(x2, sh), sy2 = __fadd_rn(y2, sh);
        shifted[o * 4 + 0] = sx1; shifted[o * 4 + 1] = sy1;
        shifted[o * 4 + 2] = sx2; shifted[o * 4 + 3] = sy2;
        area[o] = __fmul_rn(__fsub_rn(sx2, sx1), __fsub_rn(sy2, sy1));
    }
}

// ---------------------------------------------------------------------------
// Kernel 3: transposed IoU bitmask, triangular grid packing. Also emits
// nzT[b][jb][ib] (bit t <=> row j0+t has any suppressor in chunk ib) so the
// reduce kernel's round 1 reads 8 KB instead of ~270 KB per batch.
// ---------------------------------------------------------------------------
__global__ void nms_mask_kernel(const float* __restrict__ shifted,
                                const float* __restrict__ area,
                                unsigned long long* __restrict__ maskT,
                                unsigned long long* __restrict__ nzT) {
    int L = blockIdx.x, b = blockIdx.y;
    int jb = (int)((__fsqrt_rn(8.0f * (float)L + 1.0f) - 1.0f) * 0.5f);
    while ((jb + 1) * (jb + 2) / 2 <= L) ++jb;   // fixup fp error
    while (jb * (jb + 1) / 2 > L) --jb;
    int ib = L - jb * (jb + 1) / 2;
    int t = threadIdx.x;   // 0..63
    int i = ib * 64 + t;

    __shared__ float jbox[64][4];
    __shared__ float jarea[64];
    int j0 = jb * 64;
    {
        const float* sb = shifted + ((size_t)b * K + j0 + t) * 4;
        jbox[t][0] = sb[0]; jbox[t][1] = sb[1]; jbox[t][2] = sb[2]; jbox[t][3] = sb[3];
        jarea[t] = area[b * K + j0 + t];
    }
    __syncthreads();

    const float* ab = shifted + ((size_t)b * K + i) * 4;
    float ax1 = ab[0], ay1 = ab[1], ax2 = ab[2], ay2 = ab[3];
    float aarea = area[b * K + i];

    unsigned long long mycol = 0ULL;
    for (int jl = 0; jl < 64; ++jl) {
        int j = j0 + jl;
        bool cond = false;
        if (j > i) {
            float lx = fmaxf(ax1, jbox[jl][0]);
            float ly = fmaxf(ay1, jbox[jl][1]);
            float rx = fminf(ax2, jbox[jl][2]);
            float ry = fminf(ay2, jbox[jl][3]);
            float w = fmaxf(__fsub_rn(rx, lx), 0.0f);
            float h = fmaxf(__fsub_rn(ry, ly), 0.0f);
            float inter = __fmul_rn(w, h);
            float denom = __fadd_rn(__fsub_rn(__fadd_rn(aarea, jarea[jl]), inter), 1e-9f);
            float iou = __fdiv_rn(inter, denom);   // exact ref order + division
            cond = iou > 0.6f;
        }
        unsigned long long colm = __ballot(cond);
        if (t == jl) mycol = colm;
    }
    maskT[((size_t)b * K + j0 + t) * NCHUNK + ib] = mycol;
    unsigned long long nzb = __ballot(mycol != 0ULL);
    if (t == 0) nzT[((size_t)b * NCHUNK + jb) * NCHUNK + ib] = nzb;
}

// ---------------------------------------------------------------------------
// Kernel 4: parallel fixpoint greedy reduce + fused top-300 output.
// Round 1 uses the nzT summary (coalesced 32 words per chunk, wave-OR);
// only the ~1% chained rows touch full maskT rows in later rounds.
// ---------------------------------------------------------------------------
__global__ void __launch_bounds__(1024)
nms_reduce_out_kernel(const unsigned long long* __restrict__ maskT,
                      const unsigned long long* __restrict__ nzT,
                      const float* __restrict__ top_s,
                      const float* __restrict__ boxes,
                      const int* __restrict__ clsk,
                      float* __restrict__ out) {
    int b = blockIdx.x;
    int t = threadIdx.x;
    int ln = t & 63, wv = t >> 6;   // 16 waves
    __shared__ unsigned long long kept[NCHUNK], decided[NCHUNK];
    __shared__ unsigned long long snapk[NCHUNK], snapd[NCHUNK];
    __shared__ int nundec;
    if (t == 0) nundec = 0;
    __syncthreads();

    int st[2];   // 1 = decided
    #pragma unroll
    for (int h = 0; h < 2; ++h) {
        int c = wv + h * 16;                 // chunk handled by this wave
        int j = c * 64 + ln;                 // == t + h*1024
        // anysup: OR over ib of nzT[b][c][ib]; bit ln = row j has a suppressor
        unsigned long long w = (ln < NCHUNK)
            ? nzT[((size_t)b * NCHUNK + c) * NCHUNK + ln] : 0ULL;
        #pragma unroll
        for (int m = 1; m < 64; m <<= 1) w |= __shfl_xor(w, m, 64);
        bool valid = top_s[b * K + j] > 0.0f;
        bool hassup = ((w >> ln) & 1ULL) != 0ULL;
        bool k_local = valid && !hassup;
        bool d_local = !valid || !hassup;
        st[h] = d_local ? 1 : 0;
        unsigned long long kb = __ballot(k_local);
        unsigned long long db = __ballot(d_local);
        if (ln == 0) {
            kept[c] = kb;
            decided[c] = db;
            if (~db != 0ULL) atomicAdd(&nundec, __popcll(~db));
        }
    }

    for (int round = 0; round < 2048; ++round) {
        __syncthreads();
        if (nundec == 0) break;
        if (t < NCHUNK) { snapd[t] = decided[t]; snapk[t] = kept[t]; }
        __syncthreads();
        #pragma unroll
        for (int h = 0; h < 2; ++h) {
            if (st[h]) continue;
            int j = t + h * 1024;
            const unsigned long long* row = maskT + ((size_t)b * K + j) * NCHUNK;
            int nw = (j >> 6) + 1;
            unsigned long long pend = 0ULL, sup = 0ULL;
            for (int w = 0; w < nw; ++w) {
                unsigned long long r = row[w];
                pend |= r & ~snapd[w];
                sup  |= r & snapk[w];
            }
            if (pend == 0ULL) {
                unsigned long long bit = 1ULL << (j & 63);
                if (sup == 0ULL) atomicOr(&kept[j >> 6], bit);
                atomicOr(&decided[j >> 6], bit);
                st[h] = 1;
                atomicSub(&nundec, 1);
            }
        }
    }
    __syncthreads();

    // fused output phase: wave 0 only (kept[] lives in LDS)
    if (wv == 0) {
        int lane = ln;
        int total = 0;
        for (int c = 0; c < NCHUNK; ++c) {
            bool k = ((kept[c] >> lane) & 1ULL) != 0ULL;
            unsigned long long m = __ballot(k);
            total += __popcll(m);
        }
        float* dets  = out + (size_t)b * MAXDET * 6;
        float* flags = out + (size_t)B * MAXDET * 6 + (size_t)b * MAXDET;
        unsigned long long below = (lane == 0) ? 0ULL : (~0ULL >> (64 - lane));
        int kc = 0, nc = 0;
        for (int c = 0; c < NCHUNK; ++c) {
            int i = c * 64 + lane;
            bool k = ((kept[c] >> lane) & 1ULL) != 0ULL;
            unsigned long long m = __ballot(k);
            int pc = __popcll(m);
            int slot = k ? (kc + __popcll(m & below))
                         : (total + nc + __popcll((~m) & below));
            if (slot < MAXDET) {
                int o = b * K + i;
                dets[slot * 6 + 0] = boxes[o * 4 + 0];
                dets[slot * 6 + 1] = boxes[o * 4 + 1];
                dets[slot * 6 + 2] = boxes[o * 4 + 2];
                dets[slot * 6 + 3] = boxes[o * 4 + 3];
                dets[slot * 6 + 4] = top_s[o];
                dets[slot * 6 + 5] = (float)clsk[o];
                flags[slot] = k ? 1.0f : 0.0f;
            }
            kc += pc;
            nc += 64 - pc;
        }
    }
}

// ---------------------------------------------------------------------------
extern "C" void kernel_launch(void* const* d_in, const int* in_sizes, int n_in,
                              void* d_out, int out_size, void* d_ws, size_t ws_size,
                              hipStream_t stream) {
    const float* x = (const float*)d_in[0];
    float* out = (float*)d_out;

    char* ws = (char*)d_ws;
    size_t off = 0;
    auto alloc = [&](size_t bytes) -> void* {
        void* p = ws + off;
        off += bytes;
        off = (off + 255) & ~(size_t)255;
        return p;
    };

    float*    scores = (float*)    alloc((size_t)B * N * 4);
    int*      cls_id = (int*)      alloc((size_t)B * N * 4);
    float*    top_s  = (float*)    alloc((size_t)B * K * 4);
    float*    boxes  = (float*)    alloc((size_t)B * K * 4 * 4);
    int*      clsk   = (int*)      alloc((size_t)B * K * 4);
    float*    shifted= (float*)    alloc((size_t)B * K * 4 * 4);
    float*    area   = (float*)    alloc((size_t)B * K * 4);
    unsigned long long* maskT = (unsigned long long*) alloc((size_t)B * K * NCHUNK * 8);
    unsigned long long* nzT   = (unsigned long long*) alloc((size_t)B * NCHUNK * NCHUNK * 8);
    (void)ws_size; // needs ~6.5 MB

    nms_score_kernel<<<dim3((N + STILE - 1) / STILE, B), 256, 0, stream>>>(x, scores, cls_id);
    nms_select_kernel<<<B, 1024, 0, stream>>>(scores, x, cls_id,
                                              top_s, boxes, clsk, shifted, area);
    nms_mask_kernel<<<dim3(NCHUNK * (NCHUNK + 1) / 2, B), 64, 0, stream>>>(shifted, area, maskT, nzT);
    nms_reduce_out_kernel<<<B, 1024, 0, stream>>>(maskT, nzT, top_s, boxes, clsk, out);
}